// Round 10
// baseline (724.456 us; speedup 1.0000x reference)
//
#include <hip/hip_runtime.h>
#include <cstdint>
#include <cstddef>

#define NUM_USERS 100000
#define NUM_ITEMS 50000
#define NUM_NODES 150000
#define NUM_EDGES 2000000
#define BATCH 16384
#define NB_SCAN ((NUM_NODES + 255) / 256)  // 586 scan blocks
#define NREP 8                             // histogram/cursor replicas (atomic contention /8)

// ---------------- init (no hipMemsetAsync anywhere) ----------------
__global__ void zero_kernel(int* __restrict__ cnt, int* __restrict__ flags) {
  int i = blockIdx.x * blockDim.x + threadIdx.x;
  if (i < NREP * NUM_NODES) cnt[i] = 0;
  if (i < NUM_NODES) flags[i] = 0;
}

__global__ void flag_kernel(const int* __restrict__ uid, const int* __restrict__ iid,
                            int* __restrict__ flags) {
  int i = blockIdx.x * blockDim.x + threadIdx.x;
  if (i < BATCH) {
    flags[uid[i]] = 1;
    flags[NUM_USERS + iid[i]] = 1;
  }
}

// ---------------- CSR construction (8-replica atomics) ----------------
__global__ void hist_kernel(const int* __restrict__ dst, int* __restrict__ cnt) {
  int e = blockIdx.x * blockDim.x + threadIdx.x;
  if (e < NUM_EDGES) {
    int r = blockIdx.x & (NREP - 1);
    atomicAdd(&cnt[r * NUM_NODES + dst[e]], 1);
  }
}

__global__ void blocksum_kernel(const int* __restrict__ cnt, int* __restrict__ bsum) {
  __shared__ int sh[256];
  int t = threadIdx.x;
  int i = blockIdx.x * 256 + t;
  int v = 0;
  if (i < NUM_NODES) {
#pragma unroll
    for (int r = 0; r < NREP; ++r) v += cnt[r * NUM_NODES + i];
  }
  sh[t] = v;
  __syncthreads();
#pragma unroll
  for (int off = 128; off; off >>= 1) {
    if (t < off) sh[t] += sh[t + off];
    __syncthreads();
  }
  if (t == 0) bsum[blockIdx.x] = sh[0];
}

__global__ void scanb_kernel(const int* __restrict__ bsum, int* __restrict__ bpre,
                             int* __restrict__ offsets) {
  __shared__ int sh[1024];
  int t = threadIdx.x;
  int v = (t < NB_SCAN) ? bsum[t] : 0;
  sh[t] = v;
  __syncthreads();
  for (int off = 1; off < 1024; off <<= 1) {
    int x = (t >= off) ? sh[t - off] : 0;
    __syncthreads();
    sh[t] += x;
    __syncthreads();
  }
  if (t < NB_SCAN) bpre[t] = sh[t] - v;
  if (t == NB_SCAN - 1) offsets[NUM_NODES] = sh[t];  // total == NUM_EDGES
}

__global__ void scanf_kernel(const int* __restrict__ cnt, const int* __restrict__ bpre,
                             int* __restrict__ offsets, int* __restrict__ rcursor) {
  __shared__ int sh[256];
  int t = threadIdx.x;
  int i = blockIdx.x * 256 + t;
  int tot = 0;
  if (i < NUM_NODES) {
#pragma unroll
    for (int r = 0; r < NREP; ++r) tot += cnt[r * NUM_NODES + i];
  }
  sh[t] = tot;
  __syncthreads();
  for (int off = 1; off < 256; off <<= 1) {
    int x = (t >= off) ? sh[t - off] : 0;
    __syncthreads();
    sh[t] += x;
    __syncthreads();
  }
  if (i < NUM_NODES) {
    int excl = bpre[blockIdx.x] + sh[t] - tot;
    offsets[i] = excl;
    int run = excl;
#pragma unroll
    for (int r = 0; r < NREP; ++r) {   // per-replica base cursors
      rcursor[r * NUM_NODES + i] = run;
      run += cnt[r * NUM_NODES + i];
    }
  }
}

__global__ void scatter_kernel(const int* __restrict__ src, const int* __restrict__ dst,
                               int* __restrict__ rcursor, int* __restrict__ src_sorted) {
  int e = blockIdx.x * blockDim.x + threadIdx.x;
  if (e < NUM_EDGES) {
    int r = blockIdx.x & (NREP - 1);
    int p = atomicAdd(&rcursor[r * NUM_NODES + dst[e]], 1);
    src_sorted[p] = src[e];
  }
}

// ---------------- projected attention vectors: w1a[h][k] = sum_f W1[k, h*64+f]*a_l[h,f]
__global__ void proj1_kernel(const float* __restrict__ W1, const float* __restrict__ a1,
                             float* __restrict__ w1a, float* __restrict__ w1b) {
  int t = threadIdx.x;  // 256 threads: h = t>>6, k = t&63
  int h = t >> 6, k = t & 63;
  float sa = 0.f, sb = 0.f;
  for (int f = 0; f < 64; ++f) {
    float w = W1[(size_t)k * 256 + h * 64 + f];
    sa += w * a1[h * 128 + f];
    sb += w * a1[h * 128 + 64 + f];
  }
  w1a[h * 64 + k] = sa;
  w1b[h * 64 + k] = sb;
}

// ---------------- e1 tables straight from embeddings ----------------
__global__ __launch_bounds__(256) void e1_kernel(
    const float* __restrict__ ut, const float* __restrict__ it,
    const float* __restrict__ w1a, const float* __restrict__ w1b,
    float* __restrict__ e1s, float* __restrict__ e1d) {
  int wid = threadIdx.x >> 6, lane = threadIdx.x & 63;
  int node = blockIdx.x * 4 + wid;
  if (node >= NUM_NODES) return;
  const float* x = (node < NUM_USERS) ? ut + (size_t)node * 64
                                      : it + (size_t)(node - NUM_USERS) * 64;
  float xv = x[lane];
#pragma unroll
  for (int h = 0; h < 4; ++h) {
    float ps = xv * w1a[h * 64 + lane];
    float pd = xv * w1b[h * 64 + lane];
#pragma unroll
    for (int off = 32; off; off >>= 1) {
      ps += __shfl_xor(ps, off, 64);
      pd += __shfl_xor(pd, off, 64);
    }
    if (lane == 0) {
      e1s[(size_t)node * 4 + h] = ps;
      e1d[(size_t)node * 4 + h] = pd;
    }
  }
}

__device__ __forceinline__ const float* row_ptr(int s, const float* __restrict__ ut,
                                                const float* __restrict__ it) {
  return (s < NUM_USERS) ? ut + (size_t)s * 64 : it + (size_t)(s - NUM_USERS) * 64;
}

__device__ __forceinline__ float lrexp(float x) {
  x = x > 0.f ? x : 0.2f * x;
  return __expf(x);
}

__device__ __forceinline__ float wnorm(float w) {
  float sum = w;
#pragma unroll
  for (int off = 32; off; off >>= 1) sum += __shfl_xor(sum, off, 64);
  return w * (1.f / (sum + 1e-8f));
}

__device__ __forceinline__ void fold4(float4& a) {
#pragma unroll
  for (int off = 16; off <= 32; off <<= 1) {
    a.x += __shfl_xor(a.x, off, 64);
    a.y += __shfl_xor(a.y, off, 64);
    a.z += __shfl_xor(a.z, off, 64);
    a.w += __shfl_xor(a.w, off, 64);
  }
}

// ---------------- edge pass: attention-weighted aggregation of RAW embeddings ----------------
// All state in NAMED registers (R7: array out-params triggered scratch demotion).
template <int HC>
__global__ __launch_bounds__(256) void aggX_kernel(
    const int* __restrict__ offsets, const int* __restrict__ srcs,
    const float* __restrict__ e1s, const float* __restrict__ e1d,
    const float* __restrict__ ut, const float* __restrict__ it,
    int hbase, float* __restrict__ aggX) {
  int wid = threadIdx.x >> 6, lane = threadIdx.x & 63;
  int node = blockIdx.x * 4 + wid;
  if (node >= NUM_NODES) return;
  int beg = offsets[node], end = offsets[node + 1];
  int deg = end - beg;

  float edv0 = 0.f, edv1 = 0.f, edv2 = 0.f, edv3 = 0.f;
  edv0 = e1d[(size_t)node * 4 + hbase];
  if constexpr (HC > 1) edv1 = e1d[(size_t)node * 4 + hbase + 1];
  if constexpr (HC > 2) {
    edv2 = e1d[(size_t)node * 4 + hbase + 2];
    edv3 = e1d[(size_t)node * 4 + hbase + 3];
  }

  if (deg <= 64) {
    int s = 0;
    float w0 = 0.f, w1 = 0.f, w2 = 0.f, w3 = 0.f;
    if (lane < deg) {
      s = srcs[beg + lane];
      if constexpr (HC == 4) {
        float4 ev = *(const float4*)(e1s + (size_t)s * 4);
        w0 = lrexp(ev.x + edv0);
        w1 = lrexp(ev.y + edv1);
        w2 = lrexp(ev.z + edv2);
        w3 = lrexp(ev.w + edv3);
      } else if constexpr (HC == 2) {
        float2 ev = *(const float2*)(e1s + (size_t)s * 4 + hbase);
        w0 = lrexp(ev.x + edv0);
        w1 = lrexp(ev.y + edv1);
      } else {
        w0 = lrexp(e1s[(size_t)s * 4 + hbase] + edv0);
      }
    }
    w0 = wnorm(w0);
    if constexpr (HC > 1) w1 = wnorm(w1);
    if constexpr (HC > 2) { w2 = wnorm(w2); w3 = wnorm(w3); }

    const int g = lane >> 4, fl = lane & 15;
    float4 acc0 = make_float4(0.f, 0.f, 0.f, 0.f);
    float4 acc1 = acc0, acc2 = acc0, acc3 = acc0;
#pragma unroll 4
    for (int e = 0; e < deg; e += 4) {
      int ei = e + g;                      // <= 63 always
      int sg = __shfl(s, ei, 64);          // s=0 for masked lanes (safe addr)
      float4 xv = *(const float4*)(row_ptr(sg, ut, it) + fl * 4);
      float wg0 = __shfl(w0, ei, 64);      // 0 for ei >= deg
      acc0.x += wg0 * xv.x; acc0.y += wg0 * xv.y;
      acc0.z += wg0 * xv.z; acc0.w += wg0 * xv.w;
      if constexpr (HC > 1) {
        float wg1 = __shfl(w1, ei, 64);
        acc1.x += wg1 * xv.x; acc1.y += wg1 * xv.y;
        acc1.z += wg1 * xv.z; acc1.w += wg1 * xv.w;
      }
      if constexpr (HC > 2) {
        float wg2 = __shfl(w2, ei, 64);
        acc2.x += wg2 * xv.x; acc2.y += wg2 * xv.y;
        acc2.z += wg2 * xv.z; acc2.w += wg2 * xv.w;
        float wg3 = __shfl(w3, ei, 64);
        acc3.x += wg3 * xv.x; acc3.y += wg3 * xv.y;
        acc3.z += wg3 * xv.z; acc3.w += wg3 * xv.w;
      }
    }
    fold4(acc0);
    if constexpr (HC > 1) fold4(acc1);
    if constexpr (HC > 2) { fold4(acc2); fold4(acc3); }

    if constexpr (HC == 4) {
      float4 o = (g == 0) ? acc0 : (g == 1) ? acc1 : (g == 2) ? acc2 : acc3;
      *(float4*)(aggX + (size_t)node * 256 + lane * 4) = o;
    } else if constexpr (HC == 2) {
      if (g < 2) {
        float4 o = (g == 0) ? acc0 : acc1;
        *(float4*)(aggX + (size_t)node * 128 + lane * 4) = o;
      }
    } else {
      if (g == 0) *(float4*)(aggX + (size_t)node * 64 + fl * 4) = acc0;
    }
  } else {
    // generic fallback (deg > 64): lane = feature, heads in named scalars
    float s0 = 0.f, s1 = 0.f, s2 = 0.f, s3 = 0.f;
    for (int e = beg + lane; e < end; e += 64) {
      int s = srcs[e];
      if constexpr (HC == 4) {
        float4 ev = *(const float4*)(e1s + (size_t)s * 4);
        s0 += lrexp(ev.x + edv0); s1 += lrexp(ev.y + edv1);
        s2 += lrexp(ev.z + edv2); s3 += lrexp(ev.w + edv3);
      } else if constexpr (HC == 2) {
        float2 ev = *(const float2*)(e1s + (size_t)s * 4 + hbase);
        s0 += lrexp(ev.x + edv0); s1 += lrexp(ev.y + edv1);
      } else {
        s0 += lrexp(e1s[(size_t)s * 4 + hbase] + edv0);
      }
    }
#pragma unroll
    for (int off = 32; off; off >>= 1) {
      s0 += __shfl_xor(s0, off, 64);
      if constexpr (HC > 1) s1 += __shfl_xor(s1, off, 64);
      if constexpr (HC > 2) {
        s2 += __shfl_xor(s2, off, 64);
        s3 += __shfl_xor(s3, off, 64);
      }
    }
    float i0 = 1.f / (s0 + 1e-8f), i1 = 1.f / (s1 + 1e-8f);
    float i2 = 1.f / (s2 + 1e-8f), i3 = 1.f / (s3 + 1e-8f);
    float a0 = 0.f, a1 = 0.f, a2 = 0.f, a3 = 0.f;
    for (int e = beg; e < end; ++e) {
      int sn = srcs[e];
      float xv = row_ptr(sn, ut, it)[lane];
      if constexpr (HC == 4) {
        float4 ev = *(const float4*)(e1s + (size_t)sn * 4);
        a0 += lrexp(ev.x + edv0) * i0 * xv;
        a1 += lrexp(ev.y + edv1) * i1 * xv;
        a2 += lrexp(ev.z + edv2) * i2 * xv;
        a3 += lrexp(ev.w + edv3) * i3 * xv;
      } else if constexpr (HC == 2) {
        float2 ev = *(const float2*)(e1s + (size_t)sn * 4 + hbase);
        a0 += lrexp(ev.x + edv0) * i0 * xv;
        a1 += lrexp(ev.y + edv1) * i1 * xv;
      } else {
        a0 += lrexp(e1s[(size_t)sn * 4 + hbase] + edv0) * i0 * xv;
      }
    }
    aggX[(size_t)node * (HC * 64) + lane] = a0;
    if constexpr (HC > 1) aggX[(size_t)node * (HC * 64) + 64 + lane] = a1;
    if constexpr (HC > 2) {
      aggX[(size_t)node * (HC * 64) + 128 + lane] = a2;
      aggX[(size_t)node * (HC * 64) + 192 + lane] = a3;
    }
  }
}

// ---------------- dense transform: h2 += elu(aggX_h @ W1_h) @ W2_h ----------------
// 64-row tiles (R8 config: 4 blocks/CU, VALUBusy 72% — 128-row tile at 2-3 blocks/CU
// was net-neutral steady-state and paid a 274 µs cold-start: latency hiding needs
// the occupancy more than the barrier amortization).
template <int HC>
__global__ __launch_bounds__(256, 3) void trans_kernel(
    const float* __restrict__ aggX, const float* __restrict__ W1,
    const float* __restrict__ W2, const float* __restrict__ a2,
    int hbase, int last, float* __restrict__ h2,
    float* __restrict__ e2s, float* __restrict__ e2d) {
  __shared__ __align__(16) float xs[64][68];   // A rows (row-major, k contiguous)
  __shared__ __align__(16) float wsm[64][68];  // W rows
  const int t = threadIdx.x;
  const int rb = blockIdx.x;
  const int j = t & 15, i = t >> 4;
  const int row0 = rb * 64;

  float acc2[4][4];
#pragma unroll
  for (int r = 0; r < 4; ++r) { acc2[r][0] = 0.f; acc2[r][1] = 0.f; acc2[r][2] = 0.f; acc2[r][3] = 0.f; }
  if (hbase != 0) {
#pragma unroll
    for (int r = 0; r < 4; ++r) {
      int grow = row0 + i * 4 + r;
      if (grow < NUM_NODES) {
        float4 v = *(const float4*)(h2 + (size_t)grow * 64 + j * 4);
        acc2[r][0] = v.x; acc2[r][1] = v.y; acc2[r][2] = v.z; acc2[r][3] = v.w;
      }
    }
  }

#pragma unroll 1
  for (int h = 0; h < HC; ++h) {
    __syncthreads();  // previous head's GEMM2 reads complete
#pragma unroll
    for (int u = 0; u < 4; ++u) {
      int idx = t + u * 256, rw = idx >> 4, f4 = idx & 15;
      int grow = row0 + rw;
      float4 v = make_float4(0.f, 0.f, 0.f, 0.f);
      if (grow < NUM_NODES)
        v = *(const float4*)(aggX + (size_t)grow * (HC * 64) + h * 64 + f4 * 4);
      *(float4*)&xs[rw][f4 * 4] = v;
      *(float4*)&wsm[rw][f4 * 4] =
          *(const float4*)(W1 + (size_t)rw * 256 + (hbase + h) * 64 + f4 * 4);
    }
    __syncthreads();

    float t1[4][4] = {{0.f,0.f,0.f,0.f},{0.f,0.f,0.f,0.f},{0.f,0.f,0.f,0.f},{0.f,0.f,0.f,0.f}};
#pragma unroll 2
    for (int k4 = 0; k4 < 16; ++k4) {
      float4 a0 = *(const float4*)&xs[i * 4 + 0][k4 * 4];
      float4 a1_ = *(const float4*)&xs[i * 4 + 1][k4 * 4];
      float4 a2_ = *(const float4*)&xs[i * 4 + 2][k4 * 4];
      float4 a3 = *(const float4*)&xs[i * 4 + 3][k4 * 4];
#pragma unroll
      for (int c = 0; c < 4; ++c) {
        float4 bv = *(const float4*)&wsm[k4 * 4 + c][j * 4];
        float av0 = (&a0.x)[c], av1 = (&a1_.x)[c], av2 = (&a2_.x)[c], av3 = (&a3.x)[c];
        t1[0][0] += av0 * bv.x; t1[0][1] += av0 * bv.y; t1[0][2] += av0 * bv.z; t1[0][3] += av0 * bv.w;
        t1[1][0] += av1 * bv.x; t1[1][1] += av1 * bv.y; t1[1][2] += av1 * bv.z; t1[1][3] += av1 * bv.w;
        t1[2][0] += av2 * bv.x; t1[2][1] += av2 * bv.y; t1[2][2] += av2 * bv.z; t1[2][3] += av2 * bv.w;
        t1[3][0] += av3 * bv.x; t1[3][1] += av3 * bv.y; t1[3][2] += av3 * bv.z; t1[3][3] += av3 * bv.w;
      }
    }
    __syncthreads();  // GEMM1 LDS reads complete before overwrite

    // ELU + write back row-major (GEMM2 reads same pattern; no transpose)
#pragma unroll
    for (int r = 0; r < 4; ++r) {
      float4 o;
      o.x = t1[r][0] > 0.f ? t1[r][0] : expm1f(t1[r][0]);
      o.y = t1[r][1] > 0.f ? t1[r][1] : expm1f(t1[r][1]);
      o.z = t1[r][2] > 0.f ? t1[r][2] : expm1f(t1[r][2]);
      o.w = t1[r][3] > 0.f ? t1[r][3] : expm1f(t1[r][3]);
      *(float4*)&xs[i * 4 + r][j * 4] = o;
    }
#pragma unroll
    for (int u = 0; u < 4; ++u) {
      int idx = t + u * 256, rw = idx >> 4, f4 = idx & 15;
      *(float4*)&wsm[rw][f4 * 4] =
          *(const float4*)(W2 + (size_t)((hbase + h) * 64 + rw) * 64 + f4 * 4);
    }
    __syncthreads();

#pragma unroll 2
    for (int k4 = 0; k4 < 16; ++k4) {
      float4 a0 = *(const float4*)&xs[i * 4 + 0][k4 * 4];
      float4 a1_ = *(const float4*)&xs[i * 4 + 1][k4 * 4];
      float4 a2_ = *(const float4*)&xs[i * 4 + 2][k4 * 4];
      float4 a3 = *(const float4*)&xs[i * 4 + 3][k4 * 4];
#pragma unroll
      for (int c = 0; c < 4; ++c) {
        float4 bv = *(const float4*)&wsm[k4 * 4 + c][j * 4];
        float av0 = (&a0.x)[c], av1 = (&a1_.x)[c], av2 = (&a2_.x)[c], av3 = (&a3.x)[c];
        acc2[0][0] += av0 * bv.x; acc2[0][1] += av0 * bv.y; acc2[0][2] += av0 * bv.z; acc2[0][3] += av0 * bv.w;
        acc2[1][0] += av1 * bv.x; acc2[1][1] += av1 * bv.y; acc2[1][2] += av1 * bv.z; acc2[1][3] += av1 * bv.w;
        acc2[2][0] += av2 * bv.x; acc2[2][1] += av2 * bv.y; acc2[2][2] += av2 * bv.z; acc2[2][3] += av2 * bv.w;
        acc2[3][0] += av3 * bv.x; acc2[3][1] += av3 * bv.y; acc2[3][2] += av3 * bv.z; acc2[3][3] += av3 * bv.w;
      }
    }
  }

#pragma unroll
  for (int r = 0; r < 4; ++r) {
    int grow = row0 + i * 4 + r;
    if (grow < NUM_NODES) {
      float4 o = make_float4(acc2[r][0], acc2[r][1], acc2[r][2], acc2[r][3]);
      *(float4*)(h2 + (size_t)grow * 64 + j * 4) = o;
    }
  }

  if (last) {
    const float4 alv = *(const float4*)(a2 + j * 4);
    const float4 arv = *(const float4*)(a2 + 64 + j * 4);
#pragma unroll
    for (int r = 0; r < 4; ++r) {
      float ps = acc2[r][0] * alv.x + acc2[r][1] * alv.y + acc2[r][2] * alv.z + acc2[r][3] * alv.w;
      float pd = acc2[r][0] * arv.x + acc2[r][1] * arv.y + acc2[r][2] * arv.z + acc2[r][3] * arv.w;
#pragma unroll
      for (int off = 1; off < 16; off <<= 1) {
        ps += __shfl_xor(ps, off, 64);
        pd += __shfl_xor(pd, off, 64);
      }
      if (j == 0) {
        int grow = row0 + i * 4 + r;
        if (grow < NUM_NODES) { e2s[grow] = ps; e2d[grow] = pd; }
      }
    }
  }
}

// ---------------- layer-2 aggregation + residual (flagged nodes only) ----------------
__global__ __launch_bounds__(256) void agg2_kernel(
    const int* __restrict__ offsets, const int* __restrict__ srcs,
    const float* __restrict__ e2s, const float* __restrict__ e2d,
    const int* __restrict__ flags, const float* __restrict__ h2,
    const float* __restrict__ ut, const float* __restrict__ it,
    float* __restrict__ hfin) {
  int wid = threadIdx.x >> 6, lane = threadIdx.x & 63;
  int node = blockIdx.x * 4 + wid;
  if (node >= NUM_NODES) return;
  if (flags[node] != 1) return;  // output never read for this node
  int beg = offsets[node], end = offsets[node + 1];
  int deg = end - beg;
  float edv = e2d[node];

  if (deg <= 64) {
    int s = 0;
    float w = 0.f;
    if (lane < deg) {
      s = srcs[beg + lane];
      w = lrexp(e2s[s] + edv);
    }
    w = wnorm(w);

    const int g = lane >> 4, fl = lane & 15;
    float4 acc = make_float4(0.f, 0.f, 0.f, 0.f);
#pragma unroll 4
    for (int e = 0; e < deg; e += 4) {
      int ei = e + g;
      int sg = __shfl(s, ei, 64);
      float wg = __shfl(w, ei, 64);  // 0 for ei >= deg
      float4 hv = *(const float4*)(h2 + (size_t)sg * 64 + fl * 4);
      acc.x += wg * hv.x; acc.y += wg * hv.y; acc.z += wg * hv.z; acc.w += wg * hv.w;
    }
    fold4(acc);
    if (g == 0) {
      const float* rp = (node < NUM_USERS) ? ut + (size_t)node * 64
                                           : it + (size_t)(node - NUM_USERS) * 64;
      float4 res = *(const float4*)(rp + fl * 4);
      acc.x += res.x; acc.y += res.y; acc.z += res.z; acc.w += res.w;
      *(float4*)(hfin + (size_t)node * 64 + fl * 4) = acc;
    }
  } else {
    float psum = 0.f;
    for (int e = beg + lane; e < end; e += 64) {
      int s = srcs[e];
      psum += lrexp(e2s[s] + edv);
    }
#pragma unroll
    for (int off = 32; off; off >>= 1) psum += __shfl_xor(psum, off, 64);
    float inv = 1.f / (psum + 1e-8f);
    float acc = 0.f;
    for (int e = beg; e < end; ++e) {
      int s0 = srcs[e];
      acc += lrexp(e2s[s0] + edv) * inv * h2[(size_t)s0 * 64 + lane];
    }
    float res = (node < NUM_USERS) ? ut[(size_t)node * 64 + lane]
                                   : it[(size_t)(node - NUM_USERS) * 64 + lane];
    hfin[(size_t)node * 64 + lane] = acc + res;
  }
}

// ---------------- final batched dot ----------------
__global__ __launch_bounds__(256) void final_kernel(
    const float* __restrict__ hf, const int* __restrict__ uid,
    const int* __restrict__ iid, float* __restrict__ out) {
  int wid = threadIdx.x >> 6, lane = threadIdx.x & 63;
  int idx = blockIdx.x * 4 + wid;
  if (idx >= BATCH) return;
  int u = uid[idx], v = iid[idx];
  float a = hf[(size_t)u * 64 + lane];
  float b = hf[(size_t)(NUM_USERS + v) * 64 + lane];
  float p = a * b;
#pragma unroll
  for (int off = 32; off; off >>= 1) p += __shfl_xor(p, off, 64);
  if (lane == 0) out[idx] = p;
}

extern "C" void kernel_launch(void* const* d_in, const int* in_sizes, int n_in,
                              void* d_out, int out_size, void* d_ws, size_t ws_size,
                              hipStream_t stream) {
  const float* user_table = (const float*)d_in[0];
  const float* item_table = (const float*)d_in[1];
  const float* W1 = (const float*)d_in[2];
  const float* a1 = (const float*)d_in[3];
  const float* W2 = (const float*)d_in[4];
  const float* a2 = (const float*)d_in[5];
  const int* edge_index = (const int*)d_in[6];
  const int* user_ids = (const int*)d_in[7];
  const int* item_ids = (const int*)d_in[8];
  float* out = (float*)d_out;

  const int* src = edge_index;
  const int* dst = edge_index + NUM_EDGES;

  // ---- workspace layout (elements), aggX sized by ws_size ----
  float* ws = (float*)d_ws;
  size_t off = 0;
  auto falloc = [&](size_t n) { float* p = ws + off; off += n; return p; };
  float* h2  = falloc((size_t)NUM_NODES * 64);
  float* e1s = falloc((size_t)NUM_NODES * 4);
  float* e1d = falloc((size_t)NUM_NODES * 4);
  float* e2s = falloc(NUM_NODES);
  float* e2d = falloc(NUM_NODES);
  float* w1a = falloc(256);
  float* w1b = falloc(256);
  int* offsets = (int*)falloc(NUM_NODES + 1);
  int* srcs    = (int*)falloc(NUM_EDGES);
  int* flags   = (int*)falloc(NUM_NODES);
  int* bsum    = (int*)falloc(NB_SCAN);
  int* bpre    = (int*)falloc(NB_SCAN);
  off = (off + 3) & ~(size_t)3;  // 16B-align aggX for float4 access
  float* aggX = ws + off;
  size_t availElems = (ws_size / 4 > off) ? (ws_size / 4 - off) : 0;

  // Replica histogram + cursors ALIAS the head of aggX (dead until after scatter):
  // keeps fixed footprint unchanged so HC=4 still fits.
  int* cnt     = (int*)aggX;               // NREP * NUM_NODES
  int* rcursor = cnt + NREP * NUM_NODES;   // NREP * NUM_NODES  (9.6 MB total)

  // head-chunk size: 4 heads in one edge pass if aggX fits, else 2, else 1
  int HC = 1;
  if (availElems >= (size_t)NUM_NODES * 256) HC = 4;
  else if (availElems >= (size_t)NUM_NODES * 128) HC = 2;
  float* hfin = aggX;  // alias: aggX dead after last trans pass

  const int eb = (NUM_EDGES + 255) / 256;
  const int nb4 = (NUM_NODES + 3) / 4;
  const int nb64 = (NUM_NODES + 63) / 64;

  zero_kernel<<<(NREP * NUM_NODES + 255) / 256, 256, 0, stream>>>(cnt, flags);
  flag_kernel<<<(BATCH + 255) / 256, 256, 0, stream>>>(user_ids, item_ids, flags);
  hist_kernel<<<eb, 256, 0, stream>>>(dst, cnt);
  blocksum_kernel<<<NB_SCAN, 256, 0, stream>>>(cnt, bsum);
  scanb_kernel<<<1, 1024, 0, stream>>>(bsum, bpre, offsets);
  scanf_kernel<<<NB_SCAN, 256, 0, stream>>>(cnt, bpre, offsets, rcursor);
  scatter_kernel<<<eb, 256, 0, stream>>>(src, dst, rcursor, srcs);

  proj1_kernel<<<1, 256, 0, stream>>>(W1, a1, w1a, w1b);
  e1_kernel<<<nb4, 256, 0, stream>>>(user_table, item_table, w1a, w1b, e1s, e1d);

  for (int hbase = 0; hbase < 4; hbase += HC) {
    int last = (hbase + HC == 4) ? 1 : 0;
    switch (HC) {
      case 4:
        aggX_kernel<4><<<nb4, 256, 0, stream>>>(offsets, srcs, e1s, e1d,
                                                user_table, item_table, hbase, aggX);
        trans_kernel<4><<<nb64, 256, 0, stream>>>(aggX, W1, W2, a2, hbase, last,
                                                  h2, e2s, e2d);
        break;
      case 2:
        aggX_kernel<2><<<nb4, 256, 0, stream>>>(offsets, srcs, e1s, e1d,
                                                user_table, item_table, hbase, aggX);
        trans_kernel<2><<<nb64, 256, 0, stream>>>(aggX, W1, W2, a2, hbase, last,
                                                  h2, e2s, e2d);
        break;
      default:
        aggX_kernel<1><<<nb4, 256, 0, stream>>>(offsets, srcs, e1s, e1d,
                                                user_table, item_table, hbase, aggX);
        trans_kernel<1><<<nb64, 256, 0, stream>>>(aggX, W1, W2, a2, hbase, last,
                                                  h2, e2s, e2d);
        break;
    }
  }

  agg2_kernel<<<nb4, 256, 0, stream>>>(offsets, srcs, e2s, e2d, flags,
                                       h2, user_table, item_table, hfin);
  final_kernel<<<(BATCH + 3) / 4, 256, 0, stream>>>(hfin, user_ids, item_ids, out);
}

// Round 11
// 712.839 us; speedup vs baseline: 1.0163x; 1.0163x over previous
//
#include <hip/hip_runtime.h>
#include <cstdint>
#include <cstddef>

#define NUM_USERS 100000
#define NUM_ITEMS 50000
#define NUM_NODES 150000
#define NUM_EDGES 2000000
#define BATCH 16384
#define NB_SCAN ((NUM_NODES + 255) / 256)  // 586 scan blocks
#define NREP 8                             // histogram/cursor replicas
#define EHALF (NUM_EDGES / 2)              // 2 edges per thread in hist/scatter

// ---------------- init (no hipMemsetAsync anywhere) ----------------
__global__ void zero_kernel(int* __restrict__ cnt, int* __restrict__ flags,
                            int* __restrict__ ncount) {
  int i = blockIdx.x * blockDim.x + threadIdx.x;
  if (i < NREP * NUM_NODES) cnt[i] = 0;
  if (i < NUM_NODES) flags[i] = 0;
  if (i == 0) *ncount = 0;
}

// flag + append first-seen batch nodes to a dense list (dedup via atomicExch)
__global__ void flag_kernel(const int* __restrict__ uid, const int* __restrict__ iid,
                            int* __restrict__ flags, int* __restrict__ nodelist,
                            int* __restrict__ ncount) {
  int i = blockIdx.x * blockDim.x + threadIdx.x;
  if (i < BATCH) {
    int u = uid[i];
    if (atomicExch(&flags[u], 1) == 0) nodelist[atomicAdd(ncount, 1)] = u;
    int v = NUM_USERS + iid[i];
    if (atomicExch(&flags[v], 1) == 0) nodelist[atomicAdd(ncount, 1)] = v;
  }
}

// ---------------- CSR construction (8-replica atomics, 2 edges/thread) ----------------
__global__ void hist_kernel(const int* __restrict__ dst, int* __restrict__ cnt) {
  int e = blockIdx.x * blockDim.x + threadIdx.x;
  if (e < EHALF) {
    int r = blockIdx.x & (NREP - 1);
    int d0 = dst[e], d1 = dst[e + EHALF];
    atomicAdd(&cnt[r * NUM_NODES + d0], 1);
    atomicAdd(&cnt[r * NUM_NODES + d1], 1);
  }
}

__global__ void blocksum_kernel(const int* __restrict__ cnt, int* __restrict__ bsum) {
  __shared__ int sh[256];
  int t = threadIdx.x;
  int i = blockIdx.x * 256 + t;
  int v = 0;
  if (i < NUM_NODES) {
#pragma unroll
    for (int r = 0; r < NREP; ++r) v += cnt[r * NUM_NODES + i];
  }
  sh[t] = v;
  __syncthreads();
#pragma unroll
  for (int off = 128; off; off >>= 1) {
    if (t < off) sh[t] += sh[t + off];
    __syncthreads();
  }
  if (t == 0) bsum[blockIdx.x] = sh[0];
}

__global__ void scanb_kernel(const int* __restrict__ bsum, int* __restrict__ bpre,
                             int* __restrict__ offsets) {
  __shared__ int sh[1024];
  int t = threadIdx.x;
  int v = (t < NB_SCAN) ? bsum[t] : 0;
  sh[t] = v;
  __syncthreads();
  for (int off = 1; off < 1024; off <<= 1) {
    int x = (t >= off) ? sh[t - off] : 0;
    __syncthreads();
    sh[t] += x;
    __syncthreads();
  }
  if (t < NB_SCAN) bpre[t] = sh[t] - v;
  if (t == NB_SCAN - 1) offsets[NUM_NODES] = sh[t];  // total == NUM_EDGES
}

__global__ void scanf_kernel(const int* __restrict__ cnt, const int* __restrict__ bpre,
                             int* __restrict__ offsets, int* __restrict__ rcursor) {
  __shared__ int sh[256];
  int t = threadIdx.x;
  int i = blockIdx.x * 256 + t;
  int tot = 0;
  if (i < NUM_NODES) {
#pragma unroll
    for (int r = 0; r < NREP; ++r) tot += cnt[r * NUM_NODES + i];
  }
  sh[t] = tot;
  __syncthreads();
  for (int off = 1; off < 256; off <<= 1) {
    int x = (t >= off) ? sh[t - off] : 0;
    __syncthreads();
    sh[t] += x;
    __syncthreads();
  }
  if (i < NUM_NODES) {
    int excl = bpre[blockIdx.x] + sh[t] - tot;
    offsets[i] = excl;
    int run = excl;
#pragma unroll
    for (int r = 0; r < NREP; ++r) {   // per-replica base cursors
      rcursor[r * NUM_NODES + i] = run;
      run += cnt[r * NUM_NODES + i];
    }
  }
}

__global__ void scatter_kernel(const int* __restrict__ src, const int* __restrict__ dst,
                               int* __restrict__ rcursor, int* __restrict__ src_sorted) {
  int e = blockIdx.x * blockDim.x + threadIdx.x;
  if (e < EHALF) {
    int r = blockIdx.x & (NREP - 1);
    int d0 = dst[e], d1 = dst[e + EHALF];
    int s0 = src[e], s1 = src[e + EHALF];
    int p0 = atomicAdd(&rcursor[r * NUM_NODES + d0], 1);
    int p1 = atomicAdd(&rcursor[r * NUM_NODES + d1], 1);
    src_sorted[p0] = s0;
    src_sorted[p1] = s1;
  }
}

// ---------------- projected attention vectors: w1a[h][k] = sum_f W1[k, h*64+f]*a_l[h,f]
__global__ void proj1_kernel(const float* __restrict__ W1, const float* __restrict__ a1,
                             float* __restrict__ w1a, float* __restrict__ w1b) {
  int t = threadIdx.x;  // 256 threads: h = t>>6, k = t&63
  int h = t >> 6, k = t & 63;
  float sa = 0.f, sb = 0.f;
  for (int f = 0; f < 64; ++f) {
    float w = W1[(size_t)k * 256 + h * 64 + f];
    sa += w * a1[h * 128 + f];
    sb += w * a1[h * 128 + 64 + f];
  }
  w1a[h * 64 + k] = sa;
  w1b[h * 64 + k] = sb;
}

// ---------------- e1 tables straight from embeddings ----------------
__global__ __launch_bounds__(256) void e1_kernel(
    const float* __restrict__ ut, const float* __restrict__ it,
    const float* __restrict__ w1a, const float* __restrict__ w1b,
    float* __restrict__ e1s, float* __restrict__ e1d) {
  int wid = threadIdx.x >> 6, lane = threadIdx.x & 63;
  int node = blockIdx.x * 4 + wid;
  if (node >= NUM_NODES) return;
  const float* x = (node < NUM_USERS) ? ut + (size_t)node * 64
                                      : it + (size_t)(node - NUM_USERS) * 64;
  float xv = x[lane];
#pragma unroll
  for (int h = 0; h < 4; ++h) {
    float ps = xv * w1a[h * 64 + lane];
    float pd = xv * w1b[h * 64 + lane];
#pragma unroll
    for (int off = 32; off; off >>= 1) {
      ps += __shfl_xor(ps, off, 64);
      pd += __shfl_xor(pd, off, 64);
    }
    if (lane == 0) {
      e1s[(size_t)node * 4 + h] = ps;
      e1d[(size_t)node * 4 + h] = pd;
    }
  }
}

__device__ __forceinline__ const float* row_ptr(int s, const float* __restrict__ ut,
                                                const float* __restrict__ it) {
  return (s < NUM_USERS) ? ut + (size_t)s * 64 : it + (size_t)(s - NUM_USERS) * 64;
}

__device__ __forceinline__ float lrexp(float x) {
  x = x > 0.f ? x : 0.2f * x;
  return __expf(x);
}

__device__ __forceinline__ float wnorm(float w) {
  float sum = w;
#pragma unroll
  for (int off = 32; off; off >>= 1) sum += __shfl_xor(sum, off, 64);
  return w * (1.f / (sum + 1e-8f));
}

__device__ __forceinline__ void fold4(float4& a) {
#pragma unroll
  for (int off = 16; off <= 32; off <<= 1) {
    a.x += __shfl_xor(a.x, off, 64);
    a.y += __shfl_xor(a.y, off, 64);
    a.z += __shfl_xor(a.z, off, 64);
    a.w += __shfl_xor(a.w, off, 64);
  }
}

// ---------------- edge pass: attention-weighted aggregation of RAW embeddings ----------------
// All state in NAMED registers (R7: array out-params triggered scratch demotion).
template <int HC>
__global__ __launch_bounds__(256) void aggX_kernel(
    const int* __restrict__ offsets, const int* __restrict__ srcs,
    const float* __restrict__ e1s, const float* __restrict__ e1d,
    const float* __restrict__ ut, const float* __restrict__ it,
    int hbase, float* __restrict__ aggX) {
  int wid = threadIdx.x >> 6, lane = threadIdx.x & 63;
  int node = blockIdx.x * 4 + wid;
  if (node >= NUM_NODES) return;
  int beg = offsets[node], end = offsets[node + 1];
  int deg = end - beg;

  float edv0 = 0.f, edv1 = 0.f, edv2 = 0.f, edv3 = 0.f;
  edv0 = e1d[(size_t)node * 4 + hbase];
  if constexpr (HC > 1) edv1 = e1d[(size_t)node * 4 + hbase + 1];
  if constexpr (HC > 2) {
    edv2 = e1d[(size_t)node * 4 + hbase + 2];
    edv3 = e1d[(size_t)node * 4 + hbase + 3];
  }

  if (deg <= 64) {
    int s = 0;
    float w0 = 0.f, w1 = 0.f, w2 = 0.f, w3 = 0.f;
    if (lane < deg) {
      s = srcs[beg + lane];
      if constexpr (HC == 4) {
        float4 ev = *(const float4*)(e1s + (size_t)s * 4);
        w0 = lrexp(ev.x + edv0);
        w1 = lrexp(ev.y + edv1);
        w2 = lrexp(ev.z + edv2);
        w3 = lrexp(ev.w + edv3);
      } else if constexpr (HC == 2) {
        float2 ev = *(const float2*)(e1s + (size_t)s * 4 + hbase);
        w0 = lrexp(ev.x + edv0);
        w1 = lrexp(ev.y + edv1);
      } else {
        w0 = lrexp(e1s[(size_t)s * 4 + hbase] + edv0);
      }
    }
    w0 = wnorm(w0);
    if constexpr (HC > 1) w1 = wnorm(w1);
    if constexpr (HC > 2) { w2 = wnorm(w2); w3 = wnorm(w3); }

    const int g = lane >> 4, fl = lane & 15;
    float4 acc0 = make_float4(0.f, 0.f, 0.f, 0.f);
    float4 acc1 = acc0, acc2 = acc0, acc3 = acc0;
#pragma unroll 4
    for (int e = 0; e < deg; e += 4) {
      int ei = e + g;                      // <= 63 always
      int sg = __shfl(s, ei, 64);          // s=0 for masked lanes (safe addr)
      float4 xv = *(const float4*)(row_ptr(sg, ut, it) + fl * 4);
      float wg0 = __shfl(w0, ei, 64);      // 0 for ei >= deg
      acc0.x += wg0 * xv.x; acc0.y += wg0 * xv.y;
      acc0.z += wg0 * xv.z; acc0.w += wg0 * xv.w;
      if constexpr (HC > 1) {
        float wg1 = __shfl(w1, ei, 64);
        acc1.x += wg1 * xv.x; acc1.y += wg1 * xv.y;
        acc1.z += wg1 * xv.z; acc1.w += wg1 * xv.w;
      }
      if constexpr (HC > 2) {
        float wg2 = __shfl(w2, ei, 64);
        acc2.x += wg2 * xv.x; acc2.y += wg2 * xv.y;
        acc2.z += wg2 * xv.z; acc2.w += wg2 * xv.w;
        float wg3 = __shfl(w3, ei, 64);
        acc3.x += wg3 * xv.x; acc3.y += wg3 * xv.y;
        acc3.z += wg3 * xv.z; acc3.w += wg3 * xv.w;
      }
    }
    fold4(acc0);
    if constexpr (HC > 1) fold4(acc1);
    if constexpr (HC > 2) { fold4(acc2); fold4(acc3); }

    if constexpr (HC == 4) {
      float4 o = (g == 0) ? acc0 : (g == 1) ? acc1 : (g == 2) ? acc2 : acc3;
      *(float4*)(aggX + (size_t)node * 256 + lane * 4) = o;
    } else if constexpr (HC == 2) {
      if (g < 2) {
        float4 o = (g == 0) ? acc0 : acc1;
        *(float4*)(aggX + (size_t)node * 128 + lane * 4) = o;
      }
    } else {
      if (g == 0) *(float4*)(aggX + (size_t)node * 64 + fl * 4) = acc0;
    }
  } else {
    // generic fallback (deg > 64): lane = feature, heads in named scalars
    float s0 = 0.f, s1 = 0.f, s2 = 0.f, s3 = 0.f;
    for (int e = beg + lane; e < end; e += 64) {
      int s = srcs[e];
      if constexpr (HC == 4) {
        float4 ev = *(const float4*)(e1s + (size_t)s * 4);
        s0 += lrexp(ev.x + edv0); s1 += lrexp(ev.y + edv1);
        s2 += lrexp(ev.z + edv2); s3 += lrexp(ev.w + edv3);
      } else if constexpr (HC == 2) {
        float2 ev = *(const float2*)(e1s + (size_t)s * 4 + hbase);
        s0 += lrexp(ev.x + edv0); s1 += lrexp(ev.y + edv1);
      } else {
        s0 += lrexp(e1s[(size_t)s * 4 + hbase] + edv0);
      }
    }
#pragma unroll
    for (int off = 32; off; off >>= 1) {
      s0 += __shfl_xor(s0, off, 64);
      if constexpr (HC > 1) s1 += __shfl_xor(s1, off, 64);
      if constexpr (HC > 2) {
        s2 += __shfl_xor(s2, off, 64);
        s3 += __shfl_xor(s3, off, 64);
      }
    }
    float i0 = 1.f / (s0 + 1e-8f), i1 = 1.f / (s1 + 1e-8f);
    float i2 = 1.f / (s2 + 1e-8f), i3 = 1.f / (s3 + 1e-8f);
    float a0 = 0.f, a1 = 0.f, a2 = 0.f, a3 = 0.f;
    for (int e = beg; e < end; ++e) {
      int sn = srcs[e];
      float xv = row_ptr(sn, ut, it)[lane];
      if constexpr (HC == 4) {
        float4 ev = *(const float4*)(e1s + (size_t)sn * 4);
        a0 += lrexp(ev.x + edv0) * i0 * xv;
        a1 += lrexp(ev.y + edv1) * i1 * xv;
        a2 += lrexp(ev.z + edv2) * i2 * xv;
        a3 += lrexp(ev.w + edv3) * i3 * xv;
      } else if constexpr (HC == 2) {
        float2 ev = *(const float2*)(e1s + (size_t)sn * 4 + hbase);
        a0 += lrexp(ev.x + edv0) * i0 * xv;
        a1 += lrexp(ev.y + edv1) * i1 * xv;
      } else {
        a0 += lrexp(e1s[(size_t)sn * 4 + hbase] + edv0) * i0 * xv;
      }
    }
    aggX[(size_t)node * (HC * 64) + lane] = a0;
    if constexpr (HC > 1) aggX[(size_t)node * (HC * 64) + 64 + lane] = a1;
    if constexpr (HC > 2) {
      aggX[(size_t)node * (HC * 64) + 128 + lane] = a2;
      aggX[(size_t)node * (HC * 64) + 192 + lane] = a3;
    }
  }
}

// ---------------- dense transform: h2 += elu(aggX_h @ W1_h) @ W2_h ----------------
// 64-row tiles (R8 config). 128-row tile (R9) was steady-neutral + cold-start
// regression; LDS-op:FMA ratio improvements trade against occupancy here.
template <int HC>
__global__ __launch_bounds__(256, 3) void trans_kernel(
    const float* __restrict__ aggX, const float* __restrict__ W1,
    const float* __restrict__ W2, const float* __restrict__ a2,
    int hbase, int last, float* __restrict__ h2,
    float* __restrict__ e2s, float* __restrict__ e2d) {
  __shared__ __align__(16) float xs[64][68];   // A rows (row-major, k contiguous)
  __shared__ __align__(16) float wsm[64][68];  // W rows
  const int t = threadIdx.x;
  const int rb = blockIdx.x;
  const int j = t & 15, i = t >> 4;
  const int row0 = rb * 64;

  float acc2[4][4];
#pragma unroll
  for (int r = 0; r < 4; ++r) { acc2[r][0] = 0.f; acc2[r][1] = 0.f; acc2[r][2] = 0.f; acc2[r][3] = 0.f; }
  if (hbase != 0) {
#pragma unroll
    for (int r = 0; r < 4; ++r) {
      int grow = row0 + i * 4 + r;
      if (grow < NUM_NODES) {
        float4 v = *(const float4*)(h2 + (size_t)grow * 64 + j * 4);
        acc2[r][0] = v.x; acc2[r][1] = v.y; acc2[r][2] = v.z; acc2[r][3] = v.w;
      }
    }
  }

#pragma unroll 1
  for (int h = 0; h < HC; ++h) {
    __syncthreads();  // previous head's GEMM2 reads complete
#pragma unroll
    for (int u = 0; u < 4; ++u) {
      int idx = t + u * 256, rw = idx >> 4, f4 = idx & 15;
      int grow = row0 + rw;
      float4 v = make_float4(0.f, 0.f, 0.f, 0.f);
      if (grow < NUM_NODES)
        v = *(const float4*)(aggX + (size_t)grow * (HC * 64) + h * 64 + f4 * 4);
      *(float4*)&xs[rw][f4 * 4] = v;
      *(float4*)&wsm[rw][f4 * 4] =
          *(const float4*)(W1 + (size_t)rw * 256 + (hbase + h) * 64 + f4 * 4);
    }
    __syncthreads();

    float t1[4][4] = {{0.f,0.f,0.f,0.f},{0.f,0.f,0.f,0.f},{0.f,0.f,0.f,0.f},{0.f,0.f,0.f,0.f}};
#pragma unroll 2
    for (int k4 = 0; k4 < 16; ++k4) {
      float4 a0 = *(const float4*)&xs[i * 4 + 0][k4 * 4];
      float4 a1_ = *(const float4*)&xs[i * 4 + 1][k4 * 4];
      float4 a2_ = *(const float4*)&xs[i * 4 + 2][k4 * 4];
      float4 a3 = *(const float4*)&xs[i * 4 + 3][k4 * 4];
#pragma unroll
      for (int c = 0; c < 4; ++c) {
        float4 bv = *(const float4*)&wsm[k4 * 4 + c][j * 4];
        float av0 = (&a0.x)[c], av1 = (&a1_.x)[c], av2 = (&a2_.x)[c], av3 = (&a3.x)[c];
        t1[0][0] += av0 * bv.x; t1[0][1] += av0 * bv.y; t1[0][2] += av0 * bv.z; t1[0][3] += av0 * bv.w;
        t1[1][0] += av1 * bv.x; t1[1][1] += av1 * bv.y; t1[1][2] += av1 * bv.z; t1[1][3] += av1 * bv.w;
        t1[2][0] += av2 * bv.x; t1[2][1] += av2 * bv.y; t1[2][2] += av2 * bv.z; t1[2][3] += av2 * bv.w;
        t1[3][0] += av3 * bv.x; t1[3][1] += av3 * bv.y; t1[3][2] += av3 * bv.z; t1[3][3] += av3 * bv.w;
      }
    }
    __syncthreads();  // GEMM1 LDS reads complete before overwrite

    // ELU + write back row-major (GEMM2 reads same pattern; no transpose)
#pragma unroll
    for (int r = 0; r < 4; ++r) {
      float4 o;
      o.x = t1[r][0] > 0.f ? t1[r][0] : expm1f(t1[r][0]);
      o.y = t1[r][1] > 0.f ? t1[r][1] : expm1f(t1[r][1]);
      o.z = t1[r][2] > 0.f ? t1[r][2] : expm1f(t1[r][2]);
      o.w = t1[r][3] > 0.f ? t1[r][3] : expm1f(t1[r][3]);
      *(float4*)&xs[i * 4 + r][j * 4] = o;
    }
#pragma unroll
    for (int u = 0; u < 4; ++u) {
      int idx = t + u * 256, rw = idx >> 4, f4 = idx & 15;
      *(float4*)&wsm[rw][f4 * 4] =
          *(const float4*)(W2 + (size_t)((hbase + h) * 64 + rw) * 64 + f4 * 4);
    }
    __syncthreads();

#pragma unroll 2
    for (int k4 = 0; k4 < 16; ++k4) {
      float4 a0 = *(const float4*)&xs[i * 4 + 0][k4 * 4];
      float4 a1_ = *(const float4*)&xs[i * 4 + 1][k4 * 4];
      float4 a2_ = *(const float4*)&xs[i * 4 + 2][k4 * 4];
      float4 a3 = *(const float4*)&xs[i * 4 + 3][k4 * 4];
#pragma unroll
      for (int c = 0; c < 4; ++c) {
        float4 bv = *(const float4*)&wsm[k4 * 4 + c][j * 4];
        float av0 = (&a0.x)[c], av1 = (&a1_.x)[c], av2 = (&a2_.x)[c], av3 = (&a3.x)[c];
        acc2[0][0] += av0 * bv.x; acc2[0][1] += av0 * bv.y; acc2[0][2] += av0 * bv.z; acc2[0][3] += av0 * bv.w;
        acc2[1][0] += av1 * bv.x; acc2[1][1] += av1 * bv.y; acc2[1][2] += av1 * bv.z; acc2[1][3] += av1 * bv.w;
        acc2[2][0] += av2 * bv.x; acc2[2][1] += av2 * bv.y; acc2[2][2] += av2 * bv.z; acc2[2][3] += av2 * bv.w;
        acc2[3][0] += av3 * bv.x; acc2[3][1] += av3 * bv.y; acc2[3][2] += av3 * bv.z; acc2[3][3] += av3 * bv.w;
      }
    }
  }

#pragma unroll
  for (int r = 0; r < 4; ++r) {
    int grow = row0 + i * 4 + r;
    if (grow < NUM_NODES) {
      float4 o = make_float4(acc2[r][0], acc2[r][1], acc2[r][2], acc2[r][3]);
      *(float4*)(h2 + (size_t)grow * 64 + j * 4) = o;
    }
  }

  if (last) {
    const float4 alv = *(const float4*)(a2 + j * 4);
    const float4 arv = *(const float4*)(a2 + 64 + j * 4);
#pragma unroll
    for (int r = 0; r < 4; ++r) {
      float ps = acc2[r][0] * alv.x + acc2[r][1] * alv.y + acc2[r][2] * alv.z + acc2[r][3] * alv.w;
      float pd = acc2[r][0] * arv.x + acc2[r][1] * arv.y + acc2[r][2] * arv.z + acc2[r][3] * arv.w;
#pragma unroll
      for (int off = 1; off < 16; off <<= 1) {
        ps += __shfl_xor(ps, off, 64);
        pd += __shfl_xor(pd, off, 64);
      }
      if (j == 0) {
        int grow = row0 + i * 4 + r;
        if (grow < NUM_NODES) { e2s[grow] = ps; e2d[grow] = pd; }
      }
    }
  }
}

// ---------------- layer-2 aggregation + residual (listed nodes only) ----------------
__global__ __launch_bounds__(256) void agg2_kernel(
    const int* __restrict__ offsets, const int* __restrict__ srcs,
    const float* __restrict__ e2s, const float* __restrict__ e2d,
    const int* __restrict__ nodelist, const int* __restrict__ ncount,
    const float* __restrict__ h2,
    const float* __restrict__ ut, const float* __restrict__ it,
    float* __restrict__ hfin) {
  int wid = threadIdx.x >> 6, lane = threadIdx.x & 63;
  int idx = blockIdx.x * 4 + wid;
  if (idx >= *ncount) return;
  int node = nodelist[idx];
  int beg = offsets[node], end = offsets[node + 1];
  int deg = end - beg;
  float edv = e2d[node];

  if (deg <= 64) {
    int s = 0;
    float w = 0.f;
    if (lane < deg) {
      s = srcs[beg + lane];
      w = lrexp(e2s[s] + edv);
    }
    w = wnorm(w);

    const int g = lane >> 4, fl = lane & 15;
    float4 acc = make_float4(0.f, 0.f, 0.f, 0.f);
#pragma unroll 4
    for (int e = 0; e < deg; e += 4) {
      int ei = e + g;
      int sg = __shfl(s, ei, 64);
      float wg = __shfl(w, ei, 64);  // 0 for ei >= deg
      float4 hv = *(const float4*)(h2 + (size_t)sg * 64 + fl * 4);
      acc.x += wg * hv.x; acc.y += wg * hv.y; acc.z += wg * hv.z; acc.w += wg * hv.w;
    }
    fold4(acc);
    if (g == 0) {
      const float* rp = (node < NUM_USERS) ? ut + (size_t)node * 64
                                           : it + (size_t)(node - NUM_USERS) * 64;
      float4 res = *(const float4*)(rp + fl * 4);
      acc.x += res.x; acc.y += res.y; acc.z += res.z; acc.w += res.w;
      *(float4*)(hfin + (size_t)node * 64 + fl * 4) = acc;
    }
  } else {
    float psum = 0.f;
    for (int e = beg + lane; e < end; e += 64) {
      int s = srcs[e];
      psum += lrexp(e2s[s] + edv);
    }
#pragma unroll
    for (int off = 32; off; off >>= 1) psum += __shfl_xor(psum, off, 64);
    float inv = 1.f / (psum + 1e-8f);
    float acc = 0.f;
    for (int e = beg; e < end; ++e) {
      int s0 = srcs[e];
      acc += lrexp(e2s[s0] + edv) * inv * h2[(size_t)s0 * 64 + lane];
    }
    float res = (node < NUM_USERS) ? ut[(size_t)node * 64 + lane]
                                   : it[(size_t)(node - NUM_USERS) * 64 + lane];
    hfin[(size_t)node * 64 + lane] = acc + res;
  }
}

// ---------------- final batched dot ----------------
__global__ __launch_bounds__(256) void final_kernel(
    const float* __restrict__ hf, const int* __restrict__ uid,
    const int* __restrict__ iid, float* __restrict__ out) {
  int wid = threadIdx.x >> 6, lane = threadIdx.x & 63;
  int idx = blockIdx.x * 4 + wid;
  if (idx >= BATCH) return;
  int u = uid[idx], v = iid[idx];
  float a = hf[(size_t)u * 64 + lane];
  float b = hf[(size_t)(NUM_USERS + v) * 64 + lane];
  float p = a * b;
#pragma unroll
  for (int off = 32; off; off >>= 1) p += __shfl_xor(p, off, 64);
  if (lane == 0) out[idx] = p;
}

extern "C" void kernel_launch(void* const* d_in, const int* in_sizes, int n_in,
                              void* d_out, int out_size, void* d_ws, size_t ws_size,
                              hipStream_t stream) {
  const float* user_table = (const float*)d_in[0];
  const float* item_table = (const float*)d_in[1];
  const float* W1 = (const float*)d_in[2];
  const float* a1 = (const float*)d_in[3];
  const float* W2 = (const float*)d_in[4];
  const float* a2 = (const float*)d_in[5];
  const int* edge_index = (const int*)d_in[6];
  const int* user_ids = (const int*)d_in[7];
  const int* item_ids = (const int*)d_in[8];
  float* out = (float*)d_out;

  const int* src = edge_index;
  const int* dst = edge_index + NUM_EDGES;

  // ---- workspace layout (elements), aggX sized by ws_size ----
  float* ws = (float*)d_ws;
  size_t off = 0;
  auto falloc = [&](size_t n) { float* p = ws + off; off += n; return p; };
  float* h2  = falloc((size_t)NUM_NODES * 64);
  float* e1s = falloc((size_t)NUM_NODES * 4);
  float* e1d = falloc((size_t)NUM_NODES * 4);
  float* e2s = falloc(NUM_NODES);
  float* e2d = falloc(NUM_NODES);
  float* w1a = falloc(256);
  float* w1b = falloc(256);
  int* offsets  = (int*)falloc(NUM_NODES + 1);
  int* srcs     = (int*)falloc(NUM_EDGES);
  int* flags    = (int*)falloc(NUM_NODES);
  int* bsum     = (int*)falloc(NB_SCAN);
  int* bpre     = (int*)falloc(NB_SCAN);
  int* nodelist = (int*)falloc(2 * BATCH);
  int* ncount   = (int*)falloc(1);
  off = (off + 3) & ~(size_t)3;  // 16B-align aggX for float4 access
  float* aggX = ws + off;
  size_t availElems = (ws_size / 4 > off) ? (ws_size / 4 - off) : 0;

  // Replica histogram + cursors ALIAS the head of aggX (dead until after scatter).
  int* cnt     = (int*)aggX;               // NREP * NUM_NODES
  int* rcursor = cnt + NREP * NUM_NODES;   // NREP * NUM_NODES

  // head-chunk size: 4 heads in one edge pass if aggX fits, else 2, else 1
  int HC = 1;
  if (availElems >= (size_t)NUM_NODES * 256) HC = 4;
  else if (availElems >= (size_t)NUM_NODES * 128) HC = 2;
  float* hfin = aggX;  // alias: aggX dead after last trans pass

  const int eb2 = (EHALF + 255) / 256;
  const int nb4 = (NUM_NODES + 3) / 4;
  const int nb64 = (NUM_NODES + 63) / 64;

  zero_kernel<<<(NREP * NUM_NODES + 255) / 256, 256, 0, stream>>>(cnt, flags, ncount);
  flag_kernel<<<(BATCH + 255) / 256, 256, 0, stream>>>(user_ids, item_ids, flags,
                                                       nodelist, ncount);
  hist_kernel<<<eb2, 256, 0, stream>>>(dst, cnt);
  blocksum_kernel<<<NB_SCAN, 256, 0, stream>>>(cnt, bsum);
  scanb_kernel<<<1, 1024, 0, stream>>>(bsum, bpre, offsets);
  scanf_kernel<<<NB_SCAN, 256, 0, stream>>>(cnt, bpre, offsets, rcursor);
  scatter_kernel<<<eb2, 256, 0, stream>>>(src, dst, rcursor, srcs);

  proj1_kernel<<<1, 256, 0, stream>>>(W1, a1, w1a, w1b);
  e1_kernel<<<nb4, 256, 0, stream>>>(user_table, item_table, w1a, w1b, e1s, e1d);

  for (int hbase = 0; hbase < 4; hbase += HC) {
    int last = (hbase + HC == 4) ? 1 : 0;
    switch (HC) {
      case 4:
        aggX_kernel<4><<<nb4, 256, 0, stream>>>(offsets, srcs, e1s, e1d,
                                                user_table, item_table, hbase, aggX);
        trans_kernel<4><<<nb64, 256, 0, stream>>>(aggX, W1, W2, a2, hbase, last,
                                                  h2, e2s, e2d);
        break;
      case 2:
        aggX_kernel<2><<<nb4, 256, 0, stream>>>(offsets, srcs, e1s, e1d,
                                                user_table, item_table, hbase, aggX);
        trans_kernel<2><<<nb64, 256, 0, stream>>>(aggX, W1, W2, a2, hbase, last,
                                                  h2, e2s, e2d);
        break;
      default:
        aggX_kernel<1><<<nb4, 256, 0, stream>>>(offsets, srcs, e1s, e1d,
                                                user_table, item_table, hbase, aggX);
        trans_kernel<1><<<nb64, 256, 0, stream>>>(aggX, W1, W2, a2, hbase, last,
                                                  h2, e2s, e2d);
        break;
    }
  }

  agg2_kernel<<<(2 * BATCH + 3) / 4, 256, 0, stream>>>(offsets, srcs, e2s, e2d,
                                                       nodelist, ncount, h2,
                                                       user_table, item_table, hfin);
  final_kernel<<<(BATCH + 3) / 4, 256, 0, stream>>>(hfin, user_ids, item_ids, out);
}

// Round 12
// 596.535 us; speedup vs baseline: 1.2144x; 1.1950x over previous
//
#include <hip/hip_runtime.h>
#include <cstdint>
#include <cstddef>

#define NUM_USERS 100000
#define NUM_ITEMS 50000
#define NUM_NODES 150000
#define NUM_EDGES 2000000
#define BATCH 16384
#define BSHIFT 8                                   // 256 nodes per bucket
#define NBUCK ((NUM_NODES + 255) >> BSHIFT)        // 586 buckets
#define PA_EDGES 4096                              // edges per block, bhist/bpart
#define PA_BLOCKS ((NUM_EDGES + PA_EDGES - 1) / PA_EDGES)  // 489

// ---------------- init (no hipMemsetAsync anywhere) ----------------
__global__ void zero_kernel(int* __restrict__ bcnt, int* __restrict__ flags,
                            int* __restrict__ ncount) {
  int i = blockIdx.x * blockDim.x + threadIdx.x;
  if (i < NBUCK) bcnt[i] = 0;
  if (i < NUM_NODES) flags[i] = 0;
  if (i == 0) *ncount = 0;
}

// flag + append first-seen batch nodes to a dense list (dedup via atomicExch)
__global__ void flag_kernel(const int* __restrict__ uid, const int* __restrict__ iid,
                            int* __restrict__ flags, int* __restrict__ nodelist,
                            int* __restrict__ ncount) {
  int i = blockIdx.x * blockDim.x + threadIdx.x;
  if (i < BATCH) {
    int u = uid[i];
    if (atomicExch(&flags[u], 1) == 0) nodelist[atomicAdd(ncount, 1)] = u;
    int v = NUM_USERS + iid[i];
    if (atomicExch(&flags[v], 1) == 0) nodelist[atomicAdd(ncount, 1)] = v;
  }
}

// ---------------- bucketed CSR construction ----------------
// Step 1: bucket histogram, LDS-accumulated (no per-node global atomics)
__global__ __launch_bounds__(256) void bhist_kernel(const int* __restrict__ dst,
                                                    int* __restrict__ bcnt) {
  __shared__ int bh[NBUCK];
  int t = threadIdx.x;
  for (int u = t; u < NBUCK; u += 256) bh[u] = 0;
  __syncthreads();
  int base = blockIdx.x * PA_EDGES;
#pragma unroll
  for (int u = 0; u < PA_EDGES / 256; ++u) {
    int e = base + u * 256 + t;
    if (e < NUM_EDGES) atomicAdd(&bh[dst[e] >> BSHIFT], 1);
  }
  __syncthreads();
  for (int u = t; u < NBUCK; u += 256) {
    int v = bh[u];
    if (v) atomicAdd(&bcnt[u], v);
  }
}

// Step 2: scan bucket counts (586 values, one block)
__global__ void bscan_kernel(const int* __restrict__ bcnt, int* __restrict__ bbase,
                             int* __restrict__ bcursor, int* __restrict__ offsets) {
  __shared__ int sh[1024];
  int t = threadIdx.x;
  int v = (t < NBUCK) ? bcnt[t] : 0;
  sh[t] = v;
  __syncthreads();
  for (int off = 1; off < 1024; off <<= 1) {
    int x = (t >= off) ? sh[t - off] : 0;
    __syncthreads();
    sh[t] += x;
    __syncthreads();
  }
  if (t < NBUCK) {
    bbase[t] = sh[t] - v;
    bcursor[t] = sh[t] - v;
  }
  if (t == NBUCK - 1) {
    bbase[NBUCK] = sh[t];
    offsets[NUM_NODES] = sh[t];  // == NUM_EDGES
  }
}

// Step 3: partition edges into bucket regions of ebuf (packed src,dst).
// Per-block chunk reservation -> writes are short contiguous runs, not random 4B.
__global__ __launch_bounds__(256) void bpart_kernel(const int* __restrict__ src,
                                                    const int* __restrict__ dst,
                                                    int* __restrict__ bcursor,
                                                    int2* __restrict__ ebuf) {
  __shared__ int lcnt[NBUCK];
  __shared__ int lbase[NBUCK];
  int t = threadIdx.x;
  for (int u = t; u < NBUCK; u += 256) lcnt[u] = 0;
  __syncthreads();
  int base = blockIdx.x * PA_EDGES;
#pragma unroll
  for (int u = 0; u < PA_EDGES / 256; ++u) {
    int e = base + u * 256 + t;
    if (e < NUM_EDGES) atomicAdd(&lcnt[dst[e] >> BSHIFT], 1);
  }
  __syncthreads();
  for (int u = t; u < NBUCK; u += 256) {
    int v = lcnt[u];
    lbase[u] = v ? atomicAdd(&bcursor[u], v) : 0;
    lcnt[u] = 0;  // reuse as local bump
  }
  __syncthreads();
#pragma unroll
  for (int u = 0; u < PA_EDGES / 256; ++u) {
    int e = base + u * 256 + t;
    if (e < NUM_EDGES) {
      int d = dst[e];
      int b = d >> BSHIFT;
      int p = lbase[b] + atomicAdd(&lcnt[b], 1);
      ebuf[p] = make_int2(src[e], d);
    }
  }
}

// Step 4: per-bucket CSR finalize — node offsets from LDS scan (no global node
// histogram at all) + scatter into the bucket's ~13 KB region (L2-resident).
__global__ __launch_bounds__(256) void bcsr_kernel(const int2* __restrict__ ebuf,
                                                   const int* __restrict__ bbase,
                                                   int* __restrict__ offsets,
                                                   int* __restrict__ srcs) {
  __shared__ int ncnt[256];
  __shared__ int sh[256];
  __shared__ int lcur[256];
  int b = blockIdx.x;
  int t = threadIdx.x;
  int node0 = b << BSHIFT;
  int ebeg = bbase[b], eend = bbase[b + 1];
  ncnt[t] = 0;
  __syncthreads();
  for (int i = ebeg + t; i < eend; i += 256)
    atomicAdd(&ncnt[ebuf[i].y - node0], 1);
  __syncthreads();
  int v = ncnt[t];
  sh[t] = v;
  __syncthreads();
  for (int off = 1; off < 256; off <<= 1) {
    int x = (t >= off) ? sh[t - off] : 0;
    __syncthreads();
    sh[t] += x;
    __syncthreads();
  }
  int excl = ebeg + sh[t] - v;
  if (node0 + t < NUM_NODES) offsets[node0 + t] = excl;
  lcur[t] = excl;
  __syncthreads();
  for (int i = ebeg + t; i < eend; i += 256) {
    int2 ed = ebuf[i];
    int p = atomicAdd(&lcur[ed.y - node0], 1);
    srcs[p] = ed.x;
  }
}

// ---------------- projected attention vectors: w1a[h][k] = sum_f W1[k, h*64+f]*a_l[h,f]
__global__ void proj1_kernel(const float* __restrict__ W1, const float* __restrict__ a1,
                             float* __restrict__ w1a, float* __restrict__ w1b) {
  int t = threadIdx.x;  // 256 threads: h = t>>6, k = t&63
  int h = t >> 6, k = t & 63;
  float sa = 0.f, sb = 0.f;
  for (int f = 0; f < 64; ++f) {
    float w = W1[(size_t)k * 256 + h * 64 + f];
    sa += w * a1[h * 128 + f];
    sb += w * a1[h * 128 + 64 + f];
  }
  w1a[h * 64 + k] = sa;
  w1b[h * 64 + k] = sb;
}

// ---------------- e1 tables straight from embeddings ----------------
__global__ __launch_bounds__(256) void e1_kernel(
    const float* __restrict__ ut, const float* __restrict__ it,
    const float* __restrict__ w1a, const float* __restrict__ w1b,
    float* __restrict__ e1s, float* __restrict__ e1d) {
  int wid = threadIdx.x >> 6, lane = threadIdx.x & 63;
  int node = blockIdx.x * 4 + wid;
  if (node >= NUM_NODES) return;
  const float* x = (node < NUM_USERS) ? ut + (size_t)node * 64
                                      : it + (size_t)(node - NUM_USERS) * 64;
  float xv = x[lane];
#pragma unroll
  for (int h = 0; h < 4; ++h) {
    float ps = xv * w1a[h * 64 + lane];
    float pd = xv * w1b[h * 64 + lane];
#pragma unroll
    for (int off = 32; off; off >>= 1) {
      ps += __shfl_xor(ps, off, 64);
      pd += __shfl_xor(pd, off, 64);
    }
    if (lane == 0) {
      e1s[(size_t)node * 4 + h] = ps;
      e1d[(size_t)node * 4 + h] = pd;
    }
  }
}

__device__ __forceinline__ const float* row_ptr(int s, const float* __restrict__ ut,
                                                const float* __restrict__ it) {
  return (s < NUM_USERS) ? ut + (size_t)s * 64 : it + (size_t)(s - NUM_USERS) * 64;
}

__device__ __forceinline__ float lrexp(float x) {
  x = x > 0.f ? x : 0.2f * x;
  return __expf(x);
}

__device__ __forceinline__ float wnorm(float w) {
  float sum = w;
#pragma unroll
  for (int off = 32; off; off >>= 1) sum += __shfl_xor(sum, off, 64);
  return w * (1.f / (sum + 1e-8f));
}

__device__ __forceinline__ void fold4(float4& a) {
#pragma unroll
  for (int off = 16; off <= 32; off <<= 1) {
    a.x += __shfl_xor(a.x, off, 64);
    a.y += __shfl_xor(a.y, off, 64);
    a.z += __shfl_xor(a.z, off, 64);
    a.w += __shfl_xor(a.w, off, 64);
  }
}

// ---------------- edge pass: attention-weighted aggregation of RAW embeddings ----------------
// All state in NAMED registers (R7: array out-params triggered scratch demotion).
template <int HC>
__global__ __launch_bounds__(256) void aggX_kernel(
    const int* __restrict__ offsets, const int* __restrict__ srcs,
    const float* __restrict__ e1s, const float* __restrict__ e1d,
    const float* __restrict__ ut, const float* __restrict__ it,
    int hbase, float* __restrict__ aggX) {
  int wid = threadIdx.x >> 6, lane = threadIdx.x & 63;
  int node = blockIdx.x * 4 + wid;
  if (node >= NUM_NODES) return;
  int beg = offsets[node], end = offsets[node + 1];
  int deg = end - beg;

  float edv0 = 0.f, edv1 = 0.f, edv2 = 0.f, edv3 = 0.f;
  edv0 = e1d[(size_t)node * 4 + hbase];
  if constexpr (HC > 1) edv1 = e1d[(size_t)node * 4 + hbase + 1];
  if constexpr (HC > 2) {
    edv2 = e1d[(size_t)node * 4 + hbase + 2];
    edv3 = e1d[(size_t)node * 4 + hbase + 3];
  }

  if (deg <= 64) {
    int s = 0;
    float w0 = 0.f, w1 = 0.f, w2 = 0.f, w3 = 0.f;
    if (lane < deg) {
      s = srcs[beg + lane];
      if constexpr (HC == 4) {
        float4 ev = *(const float4*)(e1s + (size_t)s * 4);
        w0 = lrexp(ev.x + edv0);
        w1 = lrexp(ev.y + edv1);
        w2 = lrexp(ev.z + edv2);
        w3 = lrexp(ev.w + edv3);
      } else if constexpr (HC == 2) {
        float2 ev = *(const float2*)(e1s + (size_t)s * 4 + hbase);
        w0 = lrexp(ev.x + edv0);
        w1 = lrexp(ev.y + edv1);
      } else {
        w0 = lrexp(e1s[(size_t)s * 4 + hbase] + edv0);
      }
    }
    w0 = wnorm(w0);
    if constexpr (HC > 1) w1 = wnorm(w1);
    if constexpr (HC > 2) { w2 = wnorm(w2); w3 = wnorm(w3); }

    const int g = lane >> 4, fl = lane & 15;
    float4 acc0 = make_float4(0.f, 0.f, 0.f, 0.f);
    float4 acc1 = acc0, acc2 = acc0, acc3 = acc0;
#pragma unroll 4
    for (int e = 0; e < deg; e += 4) {
      int ei = e + g;                      // <= 63 always
      int sg = __shfl(s, ei, 64);          // s=0 for masked lanes (safe addr)
      float4 xv = *(const float4*)(row_ptr(sg, ut, it) + fl * 4);
      float wg0 = __shfl(w0, ei, 64);      // 0 for ei >= deg
      acc0.x += wg0 * xv.x; acc0.y += wg0 * xv.y;
      acc0.z += wg0 * xv.z; acc0.w += wg0 * xv.w;
      if constexpr (HC > 1) {
        float wg1 = __shfl(w1, ei, 64);
        acc1.x += wg1 * xv.x; acc1.y += wg1 * xv.y;
        acc1.z += wg1 * xv.z; acc1.w += wg1 * xv.w;
      }
      if constexpr (HC > 2) {
        float wg2 = __shfl(w2, ei, 64);
        acc2.x += wg2 * xv.x; acc2.y += wg2 * xv.y;
        acc2.z += wg2 * xv.z; acc2.w += wg2 * xv.w;
        float wg3 = __shfl(w3, ei, 64);
        acc3.x += wg3 * xv.x; acc3.y += wg3 * xv.y;
        acc3.z += wg3 * xv.z; acc3.w += wg3 * xv.w;
      }
    }
    fold4(acc0);
    if constexpr (HC > 1) fold4(acc1);
    if constexpr (HC > 2) { fold4(acc2); fold4(acc3); }

    if constexpr (HC == 4) {
      float4 o = (g == 0) ? acc0 : (g == 1) ? acc1 : (g == 2) ? acc2 : acc3;
      *(float4*)(aggX + (size_t)node * 256 + lane * 4) = o;
    } else if constexpr (HC == 2) {
      if (g < 2) {
        float4 o = (g == 0) ? acc0 : acc1;
        *(float4*)(aggX + (size_t)node * 128 + lane * 4) = o;
      }
    } else {
      if (g == 0) *(float4*)(aggX + (size_t)node * 64 + fl * 4) = acc0;
    }
  } else {
    // generic fallback (deg > 64): lane = feature, heads in named scalars
    float s0 = 0.f, s1 = 0.f, s2 = 0.f, s3 = 0.f;
    for (int e = beg + lane; e < end; e += 64) {
      int s = srcs[e];
      if constexpr (HC == 4) {
        float4 ev = *(const float4*)(e1s + (size_t)s * 4);
        s0 += lrexp(ev.x + edv0); s1 += lrexp(ev.y + edv1);
        s2 += lrexp(ev.z + edv2); s3 += lrexp(ev.w + edv3);
      } else if constexpr (HC == 2) {
        float2 ev = *(const float2*)(e1s + (size_t)s * 4 + hbase);
        s0 += lrexp(ev.x + edv0); s1 += lrexp(ev.y + edv1);
      } else {
        s0 += lrexp(e1s[(size_t)s * 4 + hbase] + edv0);
      }
    }
#pragma unroll
    for (int off = 32; off; off >>= 1) {
      s0 += __shfl_xor(s0, off, 64);
      if constexpr (HC > 1) s1 += __shfl_xor(s1, off, 64);
      if constexpr (HC > 2) {
        s2 += __shfl_xor(s2, off, 64);
        s3 += __shfl_xor(s3, off, 64);
      }
    }
    float i0 = 1.f / (s0 + 1e-8f), i1 = 1.f / (s1 + 1e-8f);
    float i2 = 1.f / (s2 + 1e-8f), i3 = 1.f / (s3 + 1e-8f);
    float a0 = 0.f, a1 = 0.f, a2 = 0.f, a3 = 0.f;
    for (int e = beg; e < end; ++e) {
      int sn = srcs[e];
      float xv = row_ptr(sn, ut, it)[lane];
      if constexpr (HC == 4) {
        float4 ev = *(const float4*)(e1s + (size_t)sn * 4);
        a0 += lrexp(ev.x + edv0) * i0 * xv;
        a1 += lrexp(ev.y + edv1) * i1 * xv;
        a2 += lrexp(ev.z + edv2) * i2 * xv;
        a3 += lrexp(ev.w + edv3) * i3 * xv;
      } else if constexpr (HC == 2) {
        float2 ev = *(const float2*)(e1s + (size_t)sn * 4 + hbase);
        a0 += lrexp(ev.x + edv0) * i0 * xv;
        a1 += lrexp(ev.y + edv1) * i1 * xv;
      } else {
        a0 += lrexp(e1s[(size_t)sn * 4 + hbase] + edv0) * i0 * xv;
      }
    }
    aggX[(size_t)node * (HC * 64) + lane] = a0;
    if constexpr (HC > 1) aggX[(size_t)node * (HC * 64) + 64 + lane] = a1;
    if constexpr (HC > 2) {
      aggX[(size_t)node * (HC * 64) + 128 + lane] = a2;
      aggX[(size_t)node * (HC * 64) + 192 + lane] = a3;
    }
  }
}

// ---------------- dense transform: h2 += elu(aggX_h @ W1_h) @ W2_h ----------------
// 64-row tiles (R8 config). 128-row tile (R9) was steady-neutral + cold-start
// regression; LDS-op:FMA ratio improvements trade against occupancy here.
template <int HC>
__global__ __launch_bounds__(256, 3) void trans_kernel(
    const float* __restrict__ aggX, const float* __restrict__ W1,
    const float* __restrict__ W2, const float* __restrict__ a2,
    int hbase, int last, float* __restrict__ h2,
    float* __restrict__ e2s, float* __restrict__ e2d) {
  __shared__ __align__(16) float xs[64][68];   // A rows (row-major, k contiguous)
  __shared__ __align__(16) float wsm[64][68];  // W rows
  const int t = threadIdx.x;
  const int rb = blockIdx.x;
  const int j = t & 15, i = t >> 4;
  const int row0 = rb * 64;

  float acc2[4][4];
#pragma unroll
  for (int r = 0; r < 4; ++r) { acc2[r][0] = 0.f; acc2[r][1] = 0.f; acc2[r][2] = 0.f; acc2[r][3] = 0.f; }
  if (hbase != 0) {
#pragma unroll
    for (int r = 0; r < 4; ++r) {
      int grow = row0 + i * 4 + r;
      if (grow < NUM_NODES) {
        float4 v = *(const float4*)(h2 + (size_t)grow * 64 + j * 4);
        acc2[r][0] = v.x; acc2[r][1] = v.y; acc2[r][2] = v.z; acc2[r][3] = v.w;
      }
    }
  }

#pragma unroll 1
  for (int h = 0; h < HC; ++h) {
    __syncthreads();  // previous head's GEMM2 reads complete
#pragma unroll
    for (int u = 0; u < 4; ++u) {
      int idx = t + u * 256, rw = idx >> 4, f4 = idx & 15;
      int grow = row0 + rw;
      float4 v = make_float4(0.f, 0.f, 0.f, 0.f);
      if (grow < NUM_NODES)
        v = *(const float4*)(aggX + (size_t)grow * (HC * 64) + h * 64 + f4 * 4);
      *(float4*)&xs[rw][f4 * 4] = v;
      *(float4*)&wsm[rw][f4 * 4] =
          *(const float4*)(W1 + (size_t)rw * 256 + (hbase + h) * 64 + f4 * 4);
    }
    __syncthreads();

    float t1[4][4] = {{0.f,0.f,0.f,0.f},{0.f,0.f,0.f,0.f},{0.f,0.f,0.f,0.f},{0.f,0.f,0.f,0.f}};
#pragma unroll 2
    for (int k4 = 0; k4 < 16; ++k4) {
      float4 a0 = *(const float4*)&xs[i * 4 + 0][k4 * 4];
      float4 a1_ = *(const float4*)&xs[i * 4 + 1][k4 * 4];
      float4 a2_ = *(const float4*)&xs[i * 4 + 2][k4 * 4];
      float4 a3 = *(const float4*)&xs[i * 4 + 3][k4 * 4];
#pragma unroll
      for (int c = 0; c < 4; ++c) {
        float4 bv = *(const float4*)&wsm[k4 * 4 + c][j * 4];
        float av0 = (&a0.x)[c], av1 = (&a1_.x)[c], av2 = (&a2_.x)[c], av3 = (&a3.x)[c];
        t1[0][0] += av0 * bv.x; t1[0][1] += av0 * bv.y; t1[0][2] += av0 * bv.z; t1[0][3] += av0 * bv.w;
        t1[1][0] += av1 * bv.x; t1[1][1] += av1 * bv.y; t1[1][2] += av1 * bv.z; t1[1][3] += av1 * bv.w;
        t1[2][0] += av2 * bv.x; t1[2][1] += av2 * bv.y; t1[2][2] += av2 * bv.z; t1[2][3] += av2 * bv.w;
        t1[3][0] += av3 * bv.x; t1[3][1] += av3 * bv.y; t1[3][2] += av3 * bv.z; t1[3][3] += av3 * bv.w;
      }
    }
    __syncthreads();  // GEMM1 LDS reads complete before overwrite

    // ELU + write back row-major (GEMM2 reads same pattern; no transpose)
#pragma unroll
    for (int r = 0; r < 4; ++r) {
      float4 o;
      o.x = t1[r][0] > 0.f ? t1[r][0] : expm1f(t1[r][0]);
      o.y = t1[r][1] > 0.f ? t1[r][1] : expm1f(t1[r][1]);
      o.z = t1[r][2] > 0.f ? t1[r][2] : expm1f(t1[r][2]);
      o.w = t1[r][3] > 0.f ? t1[r][3] : expm1f(t1[r][3]);
      *(float4*)&xs[i * 4 + r][j * 4] = o;
    }
#pragma unroll
    for (int u = 0; u < 4; ++u) {
      int idx = t + u * 256, rw = idx >> 4, f4 = idx & 15;
      *(float4*)&wsm[rw][f4 * 4] =
          *(const float4*)(W2 + (size_t)((hbase + h) * 64 + rw) * 64 + f4 * 4);
    }
    __syncthreads();

#pragma unroll 2
    for (int k4 = 0; k4 < 16; ++k4) {
      float4 a0 = *(const float4*)&xs[i * 4 + 0][k4 * 4];
      float4 a1_ = *(const float4*)&xs[i * 4 + 1][k4 * 4];
      float4 a2_ = *(const float4*)&xs[i * 4 + 2][k4 * 4];
      float4 a3 = *(const float4*)&xs[i * 4 + 3][k4 * 4];
#pragma unroll
      for (int c = 0; c < 4; ++c) {
        float4 bv = *(const float4*)&wsm[k4 * 4 + c][j * 4];
        float av0 = (&a0.x)[c], av1 = (&a1_.x)[c], av2 = (&a2_.x)[c], av3 = (&a3.x)[c];
        acc2[0][0] += av0 * bv.x; acc2[0][1] += av0 * bv.y; acc2[0][2] += av0 * bv.z; acc2[0][3] += av0 * bv.w;
        acc2[1][0] += av1 * bv.x; acc2[1][1] += av1 * bv.y; acc2[1][2] += av1 * bv.z; acc2[1][3] += av1 * bv.w;
        acc2[2][0] += av2 * bv.x; acc2[2][1] += av2 * bv.y; acc2[2][2] += av2 * bv.z; acc2[2][3] += av2 * bv.w;
        acc2[3][0] += av3 * bv.x; acc2[3][1] += av3 * bv.y; acc2[3][2] += av3 * bv.z; acc2[3][3] += av3 * bv.w;
      }
    }
  }

#pragma unroll
  for (int r = 0; r < 4; ++r) {
    int grow = row0 + i * 4 + r;
    if (grow < NUM_NODES) {
      float4 o = make_float4(acc2[r][0], acc2[r][1], acc2[r][2], acc2[r][3]);
      *(float4*)(h2 + (size_t)grow * 64 + j * 4) = o;
    }
  }

  if (last) {
    const float4 alv = *(const float4*)(a2 + j * 4);
    const float4 arv = *(const float4*)(a2 + 64 + j * 4);
#pragma unroll
    for (int r = 0; r < 4; ++r) {
      float ps = acc2[r][0] * alv.x + acc2[r][1] * alv.y + acc2[r][2] * alv.z + acc2[r][3] * alv.w;
      float pd = acc2[r][0] * arv.x + acc2[r][1] * arv.y + acc2[r][2] * arv.z + acc2[r][3] * arv.w;
#pragma unroll
      for (int off = 1; off < 16; off <<= 1) {
        ps += __shfl_xor(ps, off, 64);
        pd += __shfl_xor(pd, off, 64);
      }
      if (j == 0) {
        int grow = row0 + i * 4 + r;
        if (grow < NUM_NODES) { e2s[grow] = ps; e2d[grow] = pd; }
      }
    }
  }
}

// ---------------- layer-2 aggregation + residual (listed nodes only) ----------------
__global__ __launch_bounds__(256) void agg2_kernel(
    const int* __restrict__ offsets, const int* __restrict__ srcs,
    const float* __restrict__ e2s, const float* __restrict__ e2d,
    const int* __restrict__ nodelist, const int* __restrict__ ncount,
    const float* __restrict__ h2,
    const float* __restrict__ ut, const float* __restrict__ it,
    float* __restrict__ hfin) {
  int wid = threadIdx.x >> 6, lane = threadIdx.x & 63;
  int idx = blockIdx.x * 4 + wid;
  if (idx >= *ncount) return;
  int node = nodelist[idx];
  int beg = offsets[node], end = offsets[node + 1];
  int deg = end - beg;
  float edv = e2d[node];

  if (deg <= 64) {
    int s = 0;
    float w = 0.f;
    if (lane < deg) {
      s = srcs[beg + lane];
      w = lrexp(e2s[s] + edv);
    }
    w = wnorm(w);

    const int g = lane >> 4, fl = lane & 15;
    float4 acc = make_float4(0.f, 0.f, 0.f, 0.f);
#pragma unroll 4
    for (int e = 0; e < deg; e += 4) {
      int ei = e + g;
      int sg = __shfl(s, ei, 64);
      float wg = __shfl(w, ei, 64);  // 0 for ei >= deg
      float4 hv = *(const float4*)(h2 + (size_t)sg * 64 + fl * 4);
      acc.x += wg * hv.x; acc.y += wg * hv.y; acc.z += wg * hv.z; acc.w += wg * hv.w;
    }
    fold4(acc);
    if (g == 0) {
      const float* rp = (node < NUM_USERS) ? ut + (size_t)node * 64
                                           : it + (size_t)(node - NUM_USERS) * 64;
      float4 res = *(const float4*)(rp + fl * 4);
      acc.x += res.x; acc.y += res.y; acc.z += res.z; acc.w += res.w;
      *(float4*)(hfin + (size_t)node * 64 + fl * 4) = acc;
    }
  } else {
    float psum = 0.f;
    for (int e = beg + lane; e < end; e += 64) {
      int s = srcs[e];
      psum += lrexp(e2s[s] + edv);
    }
#pragma unroll
    for (int off = 32; off; off >>= 1) psum += __shfl_xor(psum, off, 64);
    float inv = 1.f / (psum + 1e-8f);
    float acc = 0.f;
    for (int e = beg; e < end; ++e) {
      int s0 = srcs[e];
      acc += lrexp(e2s[s0] + edv) * inv * h2[(size_t)s0 * 64 + lane];
    }
    float res = (node < NUM_USERS) ? ut[(size_t)node * 64 + lane]
                                   : it[(size_t)(node - NUM_USERS) * 64 + lane];
    hfin[(size_t)node * 64 + lane] = acc + res;
  }
}

// ---------------- final batched dot ----------------
__global__ __launch_bounds__(256) void final_kernel(
    const float* __restrict__ hf, const int* __restrict__ uid,
    const int* __restrict__ iid, float* __restrict__ out) {
  int wid = threadIdx.x >> 6, lane = threadIdx.x & 63;
  int idx = blockIdx.x * 4 + wid;
  if (idx >= BATCH) return;
  int u = uid[idx], v = iid[idx];
  float a = hf[(size_t)u * 64 + lane];
  float b = hf[(size_t)(NUM_USERS + v) * 64 + lane];
  float p = a * b;
#pragma unroll
  for (int off = 32; off; off >>= 1) p += __shfl_xor(p, off, 64);
  if (lane == 0) out[idx] = p;
}

extern "C" void kernel_launch(void* const* d_in, const int* in_sizes, int n_in,
                              void* d_out, int out_size, void* d_ws, size_t ws_size,
                              hipStream_t stream) {
  const float* user_table = (const float*)d_in[0];
  const float* item_table = (const float*)d_in[1];
  const float* W1 = (const float*)d_in[2];
  const float* a1 = (const float*)d_in[3];
  const float* W2 = (const float*)d_in[4];
  const float* a2 = (const float*)d_in[5];
  const int* edge_index = (const int*)d_in[6];
  const int* user_ids = (const int*)d_in[7];
  const int* item_ids = (const int*)d_in[8];
  float* out = (float*)d_out;

  const int* src = edge_index;
  const int* dst = edge_index + NUM_EDGES;

  // ---- workspace layout (elements), aggX sized by ws_size ----
  float* ws = (float*)d_ws;
  size_t off = 0;
  auto falloc = [&](size_t n) { float* p = ws + off; off += n; return p; };
  float* h2  = falloc((size_t)NUM_NODES * 64);
  float* e1s = falloc((size_t)NUM_NODES * 4);
  float* e1d = falloc((size_t)NUM_NODES * 4);
  float* e2s = falloc(NUM_NODES);
  float* e2d = falloc(NUM_NODES);
  float* w1a = falloc(256);
  float* w1b = falloc(256);
  int* offsets  = (int*)falloc(NUM_NODES + 1);
  int* srcs     = (int*)falloc(NUM_EDGES);
  int* flags    = (int*)falloc(NUM_NODES);
  int* nodelist = (int*)falloc(2 * BATCH);
  int* ncount   = (int*)falloc(1);
  int* bcnt     = (int*)falloc(NBUCK);
  int* bbase    = (int*)falloc(NBUCK + 1);
  int* bcursor  = (int*)falloc(NBUCK);
  off = (off + 3) & ~(size_t)3;  // 16B-align aggX for float4 access
  float* aggX = ws + off;
  size_t availElems = (ws_size / 4 > off) ? (ws_size / 4 - off) : 0;

  // ebuf (bucketed src,dst pairs, 16 MB) ALIASES the head of aggX — dead
  // before the first aggX launch.
  int2* ebuf = (int2*)aggX;

  // head-chunk size: 4 heads in one edge pass if aggX fits, else 2, else 1
  int HC = 1;
  if (availElems >= (size_t)NUM_NODES * 256) HC = 4;
  else if (availElems >= (size_t)NUM_NODES * 128) HC = 2;
  float* hfin = aggX;  // alias: aggX dead after last trans pass

  const int nb4 = (NUM_NODES + 3) / 4;
  const int nb64 = (NUM_NODES + 63) / 64;

  zero_kernel<<<(NUM_NODES + 255) / 256, 256, 0, stream>>>(bcnt, flags, ncount);
  flag_kernel<<<(BATCH + 255) / 256, 256, 0, stream>>>(user_ids, item_ids, flags,
                                                       nodelist, ncount);
  bhist_kernel<<<PA_BLOCKS, 256, 0, stream>>>(dst, bcnt);
  bscan_kernel<<<1, 1024, 0, stream>>>(bcnt, bbase, bcursor, offsets);
  bpart_kernel<<<PA_BLOCKS, 256, 0, stream>>>(src, dst, bcursor, ebuf);
  bcsr_kernel<<<NBUCK, 256, 0, stream>>>(ebuf, bbase, offsets, srcs);

  proj1_kernel<<<1, 256, 0, stream>>>(W1, a1, w1a, w1b);
  e1_kernel<<<nb4, 256, 0, stream>>>(user_table, item_table, w1a, w1b, e1s, e1d);

  for (int hbase = 0; hbase < 4; hbase += HC) {
    int last = (hbase + HC == 4) ? 1 : 0;
    switch (HC) {
      case 4:
        aggX_kernel<4><<<nb4, 256, 0, stream>>>(offsets, srcs, e1s, e1d,
                                                user_table, item_table, hbase, aggX);
        trans_kernel<4><<<nb64, 256, 0, stream>>>(aggX, W1, W2, a2, hbase, last,
                                                  h2, e2s, e2d);
        break;
      case 2:
        aggX_kernel<2><<<nb4, 256, 0, stream>>>(offsets, srcs, e1s, e1d,
                                                user_table, item_table, hbase, aggX);
        trans_kernel<2><<<nb64, 256, 0, stream>>>(aggX, W1, W2, a2, hbase, last,
                                                  h2, e2s, e2d);
        break;
      default:
        aggX_kernel<1><<<nb4, 256, 0, stream>>>(offsets, srcs, e1s, e1d,
                                                user_table, item_table, hbase, aggX);
        trans_kernel<1><<<nb64, 256, 0, stream>>>(aggX, W1, W2, a2, hbase, last,
                                                  h2, e2s, e2d);
        break;
    }
  }

  agg2_kernel<<<(2 * BATCH + 3) / 4, 256, 0, stream>>>(offsets, srcs, e2s, e2d,
                                                       nodelist, ncount, h2,
                                                       user_table, item_table, hfin);
  final_kernel<<<(BATCH + 3) / 4, 256, 0, stream>>>(hfin, user_ids, item_ids, out);
}

// Round 13
// 569.977 us; speedup vs baseline: 1.2710x; 1.0466x over previous
//
#include <hip/hip_runtime.h>
#include <cstdint>
#include <cstddef>

#define NUM_USERS 100000
#define NUM_ITEMS 50000
#define NUM_NODES 150000
#define NUM_EDGES 2000000
#define BATCH 16384
#define BSHIFT 8                                   // 256 nodes per bucket
#define NBUCK ((NUM_NODES + 255) >> BSHIFT)        // 586 buckets
#define PA_EDGES 8192                              // edges per block, bhist/bpart
#define PA_BLOCKS ((NUM_EDGES + PA_EDGES - 1) / PA_EDGES)  // 245

// ---------------- setup: nodelist (fixed 2*BATCH, dups benign) + bcnt zero ----------------
__global__ void flag_kernel(const int* __restrict__ uid, const int* __restrict__ iid,
                            int* __restrict__ nodelist, int* __restrict__ bcnt) {
  int i = blockIdx.x * blockDim.x + threadIdx.x;
  if (i < NBUCK) bcnt[i] = 0;
  if (i < BATCH) {
    nodelist[2 * i] = uid[i];
    nodelist[2 * i + 1] = NUM_USERS + iid[i];
  }
}

// ---------------- bucketed CSR construction ----------------
// Step 1: bucket histogram, LDS-accumulated (no per-node global atomics)
__global__ __launch_bounds__(256) void bhist_kernel(const int* __restrict__ dst,
                                                    int* __restrict__ bcnt) {
  __shared__ int bh[NBUCK];
  int t = threadIdx.x;
  for (int u = t; u < NBUCK; u += 256) bh[u] = 0;
  __syncthreads();
  int base = blockIdx.x * PA_EDGES;
#pragma unroll
  for (int u = 0; u < PA_EDGES / 256; ++u) {
    int e = base + u * 256 + t;
    if (e < NUM_EDGES) atomicAdd(&bh[dst[e] >> BSHIFT], 1);
  }
  __syncthreads();
  for (int u = t; u < NBUCK; u += 256) {
    int v = bh[u];
    if (v) atomicAdd(&bcnt[u], v);
  }
}

// Step 2: scan bucket counts (586 values, one block)
__global__ void bscan_kernel(const int* __restrict__ bcnt, int* __restrict__ bbase,
                             int* __restrict__ bcursor, int* __restrict__ offsets) {
  __shared__ int sh[1024];
  int t = threadIdx.x;
  int v = (t < NBUCK) ? bcnt[t] : 0;
  sh[t] = v;
  __syncthreads();
  for (int off = 1; off < 1024; off <<= 1) {
    int x = (t >= off) ? sh[t - off] : 0;
    __syncthreads();
    sh[t] += x;
    __syncthreads();
  }
  if (t < NBUCK) {
    bbase[t] = sh[t] - v;
    bcursor[t] = sh[t] - v;
  }
  if (t == NBUCK - 1) {
    bbase[NBUCK] = sh[t];
    offsets[NUM_NODES] = sh[t];  // == NUM_EDGES
  }
}

// Step 3: partition edges into bucket regions of ebuf (packed src,dst).
// Per-block chunk reservation -> writes are contiguous runs (~14 edges = 112 B).
__global__ __launch_bounds__(256) void bpart_kernel(const int* __restrict__ src,
                                                    const int* __restrict__ dst,
                                                    int* __restrict__ bcursor,
                                                    int2* __restrict__ ebuf) {
  __shared__ int lcnt[NBUCK];
  __shared__ int lbase[NBUCK];
  int t = threadIdx.x;
  for (int u = t; u < NBUCK; u += 256) lcnt[u] = 0;
  __syncthreads();
  int base = blockIdx.x * PA_EDGES;
#pragma unroll
  for (int u = 0; u < PA_EDGES / 256; ++u) {
    int e = base + u * 256 + t;
    if (e < NUM_EDGES) atomicAdd(&lcnt[dst[e] >> BSHIFT], 1);
  }
  __syncthreads();
  for (int u = t; u < NBUCK; u += 256) {
    int v = lcnt[u];
    lbase[u] = v ? atomicAdd(&bcursor[u], v) : 0;
    lcnt[u] = 0;  // reuse as local bump
  }
  __syncthreads();
#pragma unroll
  for (int u = 0; u < PA_EDGES / 256; ++u) {
    int e = base + u * 256 + t;
    if (e < NUM_EDGES) {
      int d = dst[e];
      int b = d >> BSHIFT;
      int p = lbase[b] + atomicAdd(&lcnt[b], 1);
      ebuf[p] = make_int2(src[e], d);
    }
  }
}

// Step 4: per-bucket CSR finalize — node offsets from LDS scan + scatter into the
// bucket's ~13 KB region (L2-resident; no node-level global atomics anywhere).
__global__ __launch_bounds__(256) void bcsr_kernel(const int2* __restrict__ ebuf,
                                                   const int* __restrict__ bbase,
                                                   int* __restrict__ offsets,
                                                   int* __restrict__ srcs) {
  __shared__ int ncnt[256];
  __shared__ int sh[256];
  __shared__ int lcur[256];
  int b = blockIdx.x;
  int t = threadIdx.x;
  int node0 = b << BSHIFT;
  int ebeg = bbase[b], eend = bbase[b + 1];
  ncnt[t] = 0;
  __syncthreads();
  for (int i = ebeg + t; i < eend; i += 256)
    atomicAdd(&ncnt[ebuf[i].y - node0], 1);
  __syncthreads();
  int v = ncnt[t];
  sh[t] = v;
  __syncthreads();
  for (int off = 1; off < 256; off <<= 1) {
    int x = (t >= off) ? sh[t - off] : 0;
    __syncthreads();
    sh[t] += x;
    __syncthreads();
  }
  int excl = ebeg + sh[t] - v;
  if (node0 + t < NUM_NODES) offsets[node0 + t] = excl;
  lcur[t] = excl;
  __syncthreads();
  for (int i = ebeg + t; i < eend; i += 256) {
    int2 ed = ebuf[i];
    int p = atomicAdd(&lcur[ed.y - node0], 1);
    srcs[p] = ed.x;
  }
}

// ---------------- projected attention vectors: w1a[h][k] = sum_f W1[k, h*64+f]*a_l[h,f]
__global__ void proj1_kernel(const float* __restrict__ W1, const float* __restrict__ a1,
                             float* __restrict__ w1a, float* __restrict__ w1b) {
  int t = threadIdx.x;  // 256 threads: h = t>>6, k = t&63
  int h = t >> 6, k = t & 63;
  float sa = 0.f, sb = 0.f;
  for (int f = 0; f < 64; ++f) {
    float w = W1[(size_t)k * 256 + h * 64 + f];
    sa += w * a1[h * 128 + f];
    sb += w * a1[h * 128 + 64 + f];
  }
  w1a[h * 64 + k] = sa;
  w1b[h * 64 + k] = sb;
}

// ---------------- e1 tables straight from embeddings ----------------
__global__ __launch_bounds__(256) void e1_kernel(
    const float* __restrict__ ut, const float* __restrict__ it,
    const float* __restrict__ w1a, const float* __restrict__ w1b,
    float* __restrict__ e1s, float* __restrict__ e1d) {
  int wid = threadIdx.x >> 6, lane = threadIdx.x & 63;
  int node = blockIdx.x * 4 + wid;
  if (node >= NUM_NODES) return;
  const float* x = (node < NUM_USERS) ? ut + (size_t)node * 64
                                      : it + (size_t)(node - NUM_USERS) * 64;
  float xv = x[lane];
#pragma unroll
  for (int h = 0; h < 4; ++h) {
    float ps = xv * w1a[h * 64 + lane];
    float pd = xv * w1b[h * 64 + lane];
#pragma unroll
    for (int off = 32; off; off >>= 1) {
      ps += __shfl_xor(ps, off, 64);
      pd += __shfl_xor(pd, off, 64);
    }
    if (lane == 0) {
      e1s[(size_t)node * 4 + h] = ps;
      e1d[(size_t)node * 4 + h] = pd;
    }
  }
}

__device__ __forceinline__ const float* row_ptr(int s, const float* __restrict__ ut,
                                                const float* __restrict__ it) {
  return (s < NUM_USERS) ? ut + (size_t)s * 64 : it + (size_t)(s - NUM_USERS) * 64;
}

__device__ __forceinline__ float lrexp(float x) {
  x = x > 0.f ? x : 0.2f * x;
  return __expf(x);
}

__device__ __forceinline__ float wnorm(float w) {
  float sum = w;
#pragma unroll
  for (int off = 32; off; off >>= 1) sum += __shfl_xor(sum, off, 64);
  return w * (1.f / (sum + 1e-8f));
}

__device__ __forceinline__ void fold4(float4& a) {
#pragma unroll
  for (int off = 16; off <= 32; off <<= 1) {
    a.x += __shfl_xor(a.x, off, 64);
    a.y += __shfl_xor(a.y, off, 64);
    a.z += __shfl_xor(a.z, off, 64);
    a.w += __shfl_xor(a.w, off, 64);
  }
}

// fast ELU: hardware v_exp_f32 instead of libm expm1f (abs err ~1e-7, OK at 1.7e-5 thr)
__device__ __forceinline__ float elu(float x) {
  return x > 0.f ? x : (__expf(x) - 1.f);
}

// ---------------- edge pass: attention-weighted aggregation of RAW embeddings ----------------
// All state in NAMED registers (R7: array out-params triggered scratch demotion).
template <int HC>
__global__ __launch_bounds__(256) void aggX_kernel(
    const int* __restrict__ offsets, const int* __restrict__ srcs,
    const float* __restrict__ e1s, const float* __restrict__ e1d,
    const float* __restrict__ ut, const float* __restrict__ it,
    int hbase, float* __restrict__ aggX) {
  int wid = threadIdx.x >> 6, lane = threadIdx.x & 63;
  int node = blockIdx.x * 4 + wid;
  if (node >= NUM_NODES) return;
  int beg = offsets[node], end = offsets[node + 1];
  int deg = end - beg;

  float edv0 = 0.f, edv1 = 0.f, edv2 = 0.f, edv3 = 0.f;
  edv0 = e1d[(size_t)node * 4 + hbase];
  if constexpr (HC > 1) edv1 = e1d[(size_t)node * 4 + hbase + 1];
  if constexpr (HC > 2) {
    edv2 = e1d[(size_t)node * 4 + hbase + 2];
    edv3 = e1d[(size_t)node * 4 + hbase + 3];
  }

  if (deg <= 64) {
    int s = 0;
    float w0 = 0.f, w1 = 0.f, w2 = 0.f, w3 = 0.f;
    if (lane < deg) {
      s = srcs[beg + lane];
      if constexpr (HC == 4) {
        float4 ev = *(const float4*)(e1s + (size_t)s * 4);
        w0 = lrexp(ev.x + edv0);
        w1 = lrexp(ev.y + edv1);
        w2 = lrexp(ev.z + edv2);
        w3 = lrexp(ev.w + edv3);
      } else if constexpr (HC == 2) {
        float2 ev = *(const float2*)(e1s + (size_t)s * 4 + hbase);
        w0 = lrexp(ev.x + edv0);
        w1 = lrexp(ev.y + edv1);
      } else {
        w0 = lrexp(e1s[(size_t)s * 4 + hbase] + edv0);
      }
    }
    w0 = wnorm(w0);
    if constexpr (HC > 1) w1 = wnorm(w1);
    if constexpr (HC > 2) { w2 = wnorm(w2); w3 = wnorm(w3); }

    const int g = lane >> 4, fl = lane & 15;
    float4 acc0 = make_float4(0.f, 0.f, 0.f, 0.f);
    float4 acc1 = acc0, acc2 = acc0, acc3 = acc0;
#pragma unroll 4
    for (int e = 0; e < deg; e += 4) {
      int ei = e + g;                      // <= 63 always
      int sg = __shfl(s, ei, 64);          // s=0 for masked lanes (safe addr)
      float4 xv = *(const float4*)(row_ptr(sg, ut, it) + fl * 4);
      float wg0 = __shfl(w0, ei, 64);      // 0 for ei >= deg
      acc0.x += wg0 * xv.x; acc0.y += wg0 * xv.y;
      acc0.z += wg0 * xv.z; acc0.w += wg0 * xv.w;
      if constexpr (HC > 1) {
        float wg1 = __shfl(w1, ei, 64);
        acc1.x += wg1 * xv.x; acc1.y += wg1 * xv.y;
        acc1.z += wg1 * xv.z; acc1.w += wg1 * xv.w;
      }
      if constexpr (HC > 2) {
        float wg2 = __shfl(w2, ei, 64);
        acc2.x += wg2 * xv.x; acc2.y += wg2 * xv.y;
        acc2.z += wg2 * xv.z; acc2.w += wg2 * xv.w;
        float wg3 = __shfl(w3, ei, 64);
        acc3.x += wg3 * xv.x; acc3.y += wg3 * xv.y;
        acc3.z += wg3 * xv.z; acc3.w += wg3 * xv.w;
      }
    }
    fold4(acc0);
    if constexpr (HC > 1) fold4(acc1);
    if constexpr (HC > 2) { fold4(acc2); fold4(acc3); }

    if constexpr (HC == 4) {
      float4 o = (g == 0) ? acc0 : (g == 1) ? acc1 : (g == 2) ? acc2 : acc3;
      *(float4*)(aggX + (size_t)node * 256 + lane * 4) = o;
    } else if constexpr (HC == 2) {
      if (g < 2) {
        float4 o = (g == 0) ? acc0 : acc1;
        *(float4*)(aggX + (size_t)node * 128 + lane * 4) = o;
      }
    } else {
      if (g == 0) *(float4*)(aggX + (size_t)node * 64 + fl * 4) = acc0;
    }
  } else {
    // generic fallback (deg > 64): lane = feature, heads in named scalars
    float s0 = 0.f, s1 = 0.f, s2 = 0.f, s3 = 0.f;
    for (int e = beg + lane; e < end; e += 64) {
      int s = srcs[e];
      if constexpr (HC == 4) {
        float4 ev = *(const float4*)(e1s + (size_t)s * 4);
        s0 += lrexp(ev.x + edv0); s1 += lrexp(ev.y + edv1);
        s2 += lrexp(ev.z + edv2); s3 += lrexp(ev.w + edv3);
      } else if constexpr (HC == 2) {
        float2 ev = *(const float2*)(e1s + (size_t)s * 4 + hbase);
        s0 += lrexp(ev.x + edv0); s1 += lrexp(ev.y + edv1);
      } else {
        s0 += lrexp(e1s[(size_t)s * 4 + hbase] + edv0);
      }
    }
#pragma unroll
    for (int off = 32; off; off >>= 1) {
      s0 += __shfl_xor(s0, off, 64);
      if constexpr (HC > 1) s1 += __shfl_xor(s1, off, 64);
      if constexpr (HC > 2) {
        s2 += __shfl_xor(s2, off, 64);
        s3 += __shfl_xor(s3, off, 64);
      }
    }
    float i0 = 1.f / (s0 + 1e-8f), i1 = 1.f / (s1 + 1e-8f);
    float i2 = 1.f / (s2 + 1e-8f), i3 = 1.f / (s3 + 1e-8f);
    float a0 = 0.f, a1 = 0.f, a2 = 0.f, a3 = 0.f;
    for (int e = beg; e < end; ++e) {
      int sn = srcs[e];
      float xv = row_ptr(sn, ut, it)[lane];
      if constexpr (HC == 4) {
        float4 ev = *(const float4*)(e1s + (size_t)sn * 4);
        a0 += lrexp(ev.x + edv0) * i0 * xv;
        a1 += lrexp(ev.y + edv1) * i1 * xv;
        a2 += lrexp(ev.z + edv2) * i2 * xv;
        a3 += lrexp(ev.w + edv3) * i3 * xv;
      } else if constexpr (HC == 2) {
        float2 ev = *(const float2*)(e1s + (size_t)sn * 4 + hbase);
        a0 += lrexp(ev.x + edv0) * i0 * xv;
        a1 += lrexp(ev.y + edv1) * i1 * xv;
      } else {
        a0 += lrexp(e1s[(size_t)sn * 4 + hbase] + edv0) * i0 * xv;
      }
    }
    aggX[(size_t)node * (HC * 64) + lane] = a0;
    if constexpr (HC > 1) aggX[(size_t)node * (HC * 64) + 64 + lane] = a1;
    if constexpr (HC > 2) {
      aggX[(size_t)node * (HC * 64) + 128 + lane] = a2;
      aggX[(size_t)node * (HC * 64) + 192 + lane] = a3;
    }
  }
}

// ---------------- dense transform: h2 += elu(aggX_h @ W1_h) @ W2_h ----------------
// 64-row tiles (R8 config). 128-row tile (R9) was steady-neutral + cold-start
// regression; LDS-op:FMA ratio improvements trade against occupancy here.
template <int HC>
__global__ __launch_bounds__(256, 3) void trans_kernel(
    const float* __restrict__ aggX, const float* __restrict__ W1,
    const float* __restrict__ W2, const float* __restrict__ a2,
    int hbase, int last, float* __restrict__ h2,
    float* __restrict__ e2s, float* __restrict__ e2d) {
  __shared__ __align__(16) float xs[64][68];   // A rows (row-major, k contiguous)
  __shared__ __align__(16) float wsm[64][68];  // W rows
  const int t = threadIdx.x;
  const int rb = blockIdx.x;
  const int j = t & 15, i = t >> 4;
  const int row0 = rb * 64;

  float acc2[4][4];
#pragma unroll
  for (int r = 0; r < 4; ++r) { acc2[r][0] = 0.f; acc2[r][1] = 0.f; acc2[r][2] = 0.f; acc2[r][3] = 0.f; }
  if (hbase != 0) {
#pragma unroll
    for (int r = 0; r < 4; ++r) {
      int grow = row0 + i * 4 + r;
      if (grow < NUM_NODES) {
        float4 v = *(const float4*)(h2 + (size_t)grow * 64 + j * 4);
        acc2[r][0] = v.x; acc2[r][1] = v.y; acc2[r][2] = v.z; acc2[r][3] = v.w;
      }
    }
  }

#pragma unroll 1
  for (int h = 0; h < HC; ++h) {
    __syncthreads();  // previous head's GEMM2 reads complete
#pragma unroll
    for (int u = 0; u < 4; ++u) {
      int idx = t + u * 256, rw = idx >> 4, f4 = idx & 15;
      int grow = row0 + rw;
      float4 v = make_float4(0.f, 0.f, 0.f, 0.f);
      if (grow < NUM_NODES)
        v = *(const float4*)(aggX + (size_t)grow * (HC * 64) + h * 64 + f4 * 4);
      *(float4*)&xs[rw][f4 * 4] = v;
      *(float4*)&wsm[rw][f4 * 4] =
          *(const float4*)(W1 + (size_t)rw * 256 + (hbase + h) * 64 + f4 * 4);
    }
    __syncthreads();

    float t1[4][4] = {{0.f,0.f,0.f,0.f},{0.f,0.f,0.f,0.f},{0.f,0.f,0.f,0.f},{0.f,0.f,0.f,0.f}};
#pragma unroll 2
    for (int k4 = 0; k4 < 16; ++k4) {
      float4 a0 = *(const float4*)&xs[i * 4 + 0][k4 * 4];
      float4 a1_ = *(const float4*)&xs[i * 4 + 1][k4 * 4];
      float4 a2_ = *(const float4*)&xs[i * 4 + 2][k4 * 4];
      float4 a3 = *(const float4*)&xs[i * 4 + 3][k4 * 4];
#pragma unroll
      for (int c = 0; c < 4; ++c) {
        float4 bv = *(const float4*)&wsm[k4 * 4 + c][j * 4];
        float av0 = (&a0.x)[c], av1 = (&a1_.x)[c], av2 = (&a2_.x)[c], av3 = (&a3.x)[c];
        t1[0][0] += av0 * bv.x; t1[0][1] += av0 * bv.y; t1[0][2] += av0 * bv.z; t1[0][3] += av0 * bv.w;
        t1[1][0] += av1 * bv.x; t1[1][1] += av1 * bv.y; t1[1][2] += av1 * bv.z; t1[1][3] += av1 * bv.w;
        t1[2][0] += av2 * bv.x; t1[2][1] += av2 * bv.y; t1[2][2] += av2 * bv.z; t1[2][3] += av2 * bv.w;
        t1[3][0] += av3 * bv.x; t1[3][1] += av3 * bv.y; t1[3][2] += av3 * bv.z; t1[3][3] += av3 * bv.w;
      }
    }
    __syncthreads();  // GEMM1 LDS reads complete before overwrite

    // ELU + write back row-major (GEMM2 reads same pattern; no transpose)
#pragma unroll
    for (int r = 0; r < 4; ++r) {
      float4 o;
      o.x = elu(t1[r][0]);
      o.y = elu(t1[r][1]);
      o.z = elu(t1[r][2]);
      o.w = elu(t1[r][3]);
      *(float4*)&xs[i * 4 + r][j * 4] = o;
    }
#pragma unroll
    for (int u = 0; u < 4; ++u) {
      int idx = t + u * 256, rw = idx >> 4, f4 = idx & 15;
      *(float4*)&wsm[rw][f4 * 4] =
          *(const float4*)(W2 + (size_t)((hbase + h) * 64 + rw) * 64 + f4 * 4);
    }
    __syncthreads();

#pragma unroll 2
    for (int k4 = 0; k4 < 16; ++k4) {
      float4 a0 = *(const float4*)&xs[i * 4 + 0][k4 * 4];
      float4 a1_ = *(const float4*)&xs[i * 4 + 1][k4 * 4];
      float4 a2_ = *(const float4*)&xs[i * 4 + 2][k4 * 4];
      float4 a3 = *(const float4*)&xs[i * 4 + 3][k4 * 4];
#pragma unroll
      for (int c = 0; c < 4; ++c) {
        float4 bv = *(const float4*)&wsm[k4 * 4 + c][j * 4];
        float av0 = (&a0.x)[c], av1 = (&a1_.x)[c], av2 = (&a2_.x)[c], av3 = (&a3.x)[c];
        acc2[0][0] += av0 * bv.x; acc2[0][1] += av0 * bv.y; acc2[0][2] += av0 * bv.z; acc2[0][3] += av0 * bv.w;
        acc2[1][0] += av1 * bv.x; acc2[1][1] += av1 * bv.y; acc2[1][2] += av1 * bv.z; acc2[1][3] += av1 * bv.w;
        acc2[2][0] += av2 * bv.x; acc2[2][1] += av2 * bv.y; acc2[2][2] += av2 * bv.z; acc2[2][3] += av2 * bv.w;
        acc2[3][0] += av3 * bv.x; acc2[3][1] += av3 * bv.y; acc2[3][2] += av3 * bv.z; acc2[3][3] += av3 * bv.w;
      }
    }
  }

#pragma unroll
  for (int r = 0; r < 4; ++r) {
    int grow = row0 + i * 4 + r;
    if (grow < NUM_NODES) {
      float4 o = make_float4(acc2[r][0], acc2[r][1], acc2[r][2], acc2[r][3]);
      *(float4*)(h2 + (size_t)grow * 64 + j * 4) = o;
    }
  }

  if (last) {
    const float4 alv = *(const float4*)(a2 + j * 4);
    const float4 arv = *(const float4*)(a2 + 64 + j * 4);
#pragma unroll
    for (int r = 0; r < 4; ++r) {
      float ps = acc2[r][0] * alv.x + acc2[r][1] * alv.y + acc2[r][2] * alv.z + acc2[r][3] * alv.w;
      float pd = acc2[r][0] * arv.x + acc2[r][1] * arv.y + acc2[r][2] * arv.z + acc2[r][3] * arv.w;
#pragma unroll
      for (int off = 1; off < 16; off <<= 1) {
        ps += __shfl_xor(ps, off, 64);
        pd += __shfl_xor(pd, off, 64);
      }
      if (j == 0) {
        int grow = row0 + i * 4 + r;
        if (grow < NUM_NODES) { e2s[grow] = ps; e2d[grow] = pd; }
      }
    }
  }
}

// ---------------- layer-2 aggregation + residual (listed nodes; dups benign) ----------------
__global__ __launch_bounds__(256) void agg2_kernel(
    const int* __restrict__ offsets, const int* __restrict__ srcs,
    const float* __restrict__ e2s, const float* __restrict__ e2d,
    const int* __restrict__ nodelist, const float* __restrict__ h2,
    const float* __restrict__ ut, const float* __restrict__ it,
    float* __restrict__ hfin) {
  int wid = threadIdx.x >> 6, lane = threadIdx.x & 63;
  int idx = blockIdx.x * 4 + wid;
  if (idx >= 2 * BATCH) return;
  int node = nodelist[idx];
  int beg = offsets[node], end = offsets[node + 1];
  int deg = end - beg;
  float edv = e2d[node];

  if (deg <= 64) {
    int s = 0;
    float w = 0.f;
    if (lane < deg) {
      s = srcs[beg + lane];
      w = lrexp(e2s[s] + edv);
    }
    w = wnorm(w);

    const int g = lane >> 4, fl = lane & 15;
    float4 acc = make_float4(0.f, 0.f, 0.f, 0.f);
#pragma unroll 4
    for (int e = 0; e < deg; e += 4) {
      int ei = e + g;
      int sg = __shfl(s, ei, 64);
      float wg = __shfl(w, ei, 64);  // 0 for ei >= deg
      float4 hv = *(const float4*)(h2 + (size_t)sg * 64 + fl * 4);
      acc.x += wg * hv.x; acc.y += wg * hv.y; acc.z += wg * hv.z; acc.w += wg * hv.w;
    }
    fold4(acc);
    if (g == 0) {
      const float* rp = (node < NUM_USERS) ? ut + (size_t)node * 64
                                           : it + (size_t)(node - NUM_USERS) * 64;
      float4 res = *(const float4*)(rp + fl * 4);
      acc.x += res.x; acc.y += res.y; acc.z += res.z; acc.w += res.w;
      *(float4*)(hfin + (size_t)node * 64 + fl * 4) = acc;
    }
  } else {
    float psum = 0.f;
    for (int e = beg + lane; e < end; e += 64) {
      int s = srcs[e];
      psum += lrexp(e2s[s] + edv);
    }
#pragma unroll
    for (int off = 32; off; off >>= 1) psum += __shfl_xor(psum, off, 64);
    float inv = 1.f / (psum + 1e-8f);
    float acc = 0.f;
    for (int e = beg; e < end; ++e) {
      int s0 = srcs[e];
      acc += lrexp(e2s[s0] + edv) * inv * h2[(size_t)s0 * 64 + lane];
    }
    float res = (node < NUM_USERS) ? ut[(size_t)node * 64 + lane]
                                   : it[(size_t)(node - NUM_USERS) * 64 + lane];
    hfin[(size_t)node * 64 + lane] = acc + res;
  }
}

// ---------------- final batched dot ----------------
__global__ __launch_bounds__(256) void final_kernel(
    const float* __restrict__ hf, const int* __restrict__ uid,
    const int* __restrict__ iid, float* __restrict__ out) {
  int wid = threadIdx.x >> 6, lane = threadIdx.x & 63;
  int idx = blockIdx.x * 4 + wid;
  if (idx >= BATCH) return;
  int u = uid[idx], v = iid[idx];
  float a = hf[(size_t)u * 64 + lane];
  float b = hf[(size_t)(NUM_USERS + v) * 64 + lane];
  float p = a * b;
#pragma unroll
  for (int off = 32; off; off >>= 1) p += __shfl_xor(p, off, 64);
  if (lane == 0) out[idx] = p;
}

extern "C" void kernel_launch(void* const* d_in, const int* in_sizes, int n_in,
                              void* d_out, int out_size, void* d_ws, size_t ws_size,
                              hipStream_t stream) {
  const float* user_table = (const float*)d_in[0];
  const float* item_table = (const float*)d_in[1];
  const float* W1 = (const float*)d_in[2];
  const float* a1 = (const float*)d_in[3];
  const float* W2 = (const float*)d_in[4];
  const float* a2 = (const float*)d_in[5];
  const int* edge_index = (const int*)d_in[6];
  const int* user_ids = (const int*)d_in[7];
  const int* item_ids = (const int*)d_in[8];
  float* out = (float*)d_out;

  const int* src = edge_index;
  const int* dst = edge_index + NUM_EDGES;

  // ---- workspace layout (elements), aggX sized by ws_size ----
  float* ws = (float*)d_ws;
  size_t off = 0;
  auto falloc = [&](size_t n) { float* p = ws + off; off += n; return p; };
  float* h2  = falloc((size_t)NUM_NODES * 64);
  float* e1s = falloc((size_t)NUM_NODES * 4);
  float* e1d = falloc((size_t)NUM_NODES * 4);
  float* e2s = falloc(NUM_NODES);
  float* e2d = falloc(NUM_NODES);
  float* w1a = falloc(256);
  float* w1b = falloc(256);
  int* offsets  = (int*)falloc(NUM_NODES + 1);
  int* srcs     = (int*)falloc(NUM_EDGES);
  int* nodelist = (int*)falloc(2 * BATCH);
  int* bcnt     = (int*)falloc(NBUCK);
  int* bbase    = (int*)falloc(NBUCK + 1);
  int* bcursor  = (int*)falloc(NBUCK);
  off = (off + 3) & ~(size_t)3;  // 16B-align aggX for float4 access
  float* aggX = ws + off;
  size_t availElems = (ws_size / 4 > off) ? (ws_size / 4 - off) : 0;

  // ebuf (bucketed src,dst pairs, 16 MB) ALIASES the head of aggX — dead
  // before the first aggX launch.
  int2* ebuf = (int2*)aggX;

  // head-chunk size: 4 heads in one edge pass if aggX fits, else 2, else 1
  int HC = 1;
  if (availElems >= (size_t)NUM_NODES * 256) HC = 4;
  else if (availElems >= (size_t)NUM_NODES * 128) HC = 2;
  float* hfin = aggX;  // alias: aggX dead after last trans pass

  const int nb4 = (NUM_NODES + 3) / 4;
  const int nb64 = (NUM_NODES + 63) / 64;

  flag_kernel<<<(BATCH + 255) / 256, 256, 0, stream>>>(user_ids, item_ids,
                                                       nodelist, bcnt);
  bhist_kernel<<<PA_BLOCKS, 256, 0, stream>>>(dst, bcnt);
  bscan_kernel<<<1, 1024, 0, stream>>>(bcnt, bbase, bcursor, offsets);
  bpart_kernel<<<PA_BLOCKS, 256, 0, stream>>>(src, dst, bcursor, ebuf);
  bcsr_kernel<<<NBUCK, 256, 0, stream>>>(ebuf, bbase, offsets, srcs);

  proj1_kernel<<<1, 256, 0, stream>>>(W1, a1, w1a, w1b);
  e1_kernel<<<nb4, 256, 0, stream>>>(user_table, item_table, w1a, w1b, e1s, e1d);

  for (int hbase = 0; hbase < 4; hbase += HC) {
    int last = (hbase + HC == 4) ? 1 : 0;
    switch (HC) {
      case 4:
        aggX_kernel<4><<<nb4, 256, 0, stream>>>(offsets, srcs, e1s, e1d,
                                                user_table, item_table, hbase, aggX);
        trans_kernel<4><<<nb64, 256, 0, stream>>>(aggX, W1, W2, a2, hbase, last,
                                                  h2, e2s, e2d);
        break;
      case 2:
        aggX_kernel<2><<<nb4, 256, 0, stream>>>(offsets, srcs, e1s, e1d,
                                                user_table, item_table, hbase, aggX);
        trans_kernel<2><<<nb64, 256, 0, stream>>>(aggX, W1, W2, a2, hbase, last,
                                                  h2, e2s, e2d);
        break;
      default:
        aggX_kernel<1><<<nb4, 256, 0, stream>>>(offsets, srcs, e1s, e1d,
                                                user_table, item_table, hbase, aggX);
        trans_kernel<1><<<nb64, 256, 0, stream>>>(aggX, W1, W2, a2, hbase, last,
                                                  h2, e2s, e2d);
        break;
    }
  }

  agg2_kernel<<<(2 * BATCH + 3) / 4, 256, 0, stream>>>(offsets, srcs, e2s, e2d,
                                                       nodelist, h2,
                                                       user_table, item_table, hfin);
  final_kernel<<<(BATCH + 3) / 4, 256, 0, stream>>>(hfin, user_ids, item_ids, out);
}